// Round 3
// baseline (269.869 us; speedup 1.0000x reference)
//
#include <hip/hip_runtime.h>
#include <math.h>

namespace {

constexpr int cB = 32, cL = 128, cG = 64, cD = 256;
constexpr int cHD = 128, cH = 256;
constexpr int cN = 8, cK = 4;
constexpr int cNI = 128, cRH = 512;
constexpr int cE = 2048;
constexpr float cEPS = 1e-5f;

typedef __bf16 bf16x8 __attribute__((ext_vector_type(8)));
typedef float f32x4 __attribute__((ext_vector_type(4)));

__device__ __forceinline__ f32x4 mfma16(bf16x8 a, bf16x8 b, f32x4 c) {
    return __builtin_amdgcn_mfma_f32_16x16x32_bf16(a, b, c, 0, 0, 0);
}

__device__ __forceinline__ float bf2f(unsigned short u) {
    unsigned int x = ((unsigned int)u) << 16;
    return __uint_as_float(x);
}
__device__ __forceinline__ unsigned short f2bf(float f) {
    unsigned int x = __float_as_uint(f);
    unsigned int r = (x + 0x7fffu + ((x >> 16) & 1u)) >> 16;  // RNE
    return (unsigned short)r;
}
__device__ __forceinline__ float fsig(float x) { return 1.f / (1.f + __expf(-x)); }
__device__ __forceinline__ float ftanh(float x) { return 1.f - 2.f / (__expf(2.f * x) + 1.f); }
__device__ __forceinline__ float nls(float x) {
    return (x >= 0.f) ? log1pf(expf(-x)) : (log1pf(expf(x)) - x);
}

// ---------------------------------------------------------------------------
// 1) token embedding + scatter_sum into groups, output layout (g, b, d)
__global__ void k_embed(const int* __restrict__ seq, const int* __restrict__ p2g,
                        const float* __restrict__ emb, float* __restrict__ x_seq) {
    __shared__ float xl[cG * cD];
    int b = blockIdx.x, t = threadIdx.x;
    for (int g = 0; g < cG; ++g) xl[g * cD + t] = 0.f;
    for (int l = 0; l < cL; ++l) {
        int tok = seq[b * cL + l];
        int g = p2g[b * cL + l];
        xl[g * cD + t] += emb[tok * cD + t];
    }
    for (int g = 0; g < cG; ++g)
        x_seq[(g * cB + b) * cD + t] = xl[g * cD + t];
}

// ---------------------------------------------------------------------------
// 2) LSTM input GEMM: pre[(g*32+b)][n] = x_seq row . Wcat[n] + bih+bhh
__global__ __launch_bounds__(256) void k_gemm_in(
    const float* __restrict__ x_seq,
    const float* __restrict__ wih_f, const float* __restrict__ wih_b,
    const float* __restrict__ bih_f, const float* __restrict__ bhh_f,
    const float* __restrict__ bih_b, const float* __restrict__ bhh_b,
    float* __restrict__ pre) {
    __shared__ float As[64][17];
    __shared__ float Bs[16][68];
    int t = threadIdx.x;
    int n0 = blockIdx.x * 64, m0 = blockIdx.y * 64;
    int tx = t & 15, ty = t >> 4;
    float acc[4][4] = {};
    for (int k0 = 0; k0 < cD; k0 += 16) {
        {
            int r = t >> 2, c = (t & 3) * 4;
            float4 a4 = *(const float4*)(x_seq + (size_t)(m0 + r) * cD + k0 + c);
            As[r][c + 0] = a4.x; As[r][c + 1] = a4.y; As[r][c + 2] = a4.z; As[r][c + 3] = a4.w;
        }
        {
            int n = t >> 2, c = (t & 3) * 4;
            int gn = n0 + n;
            const float* wrow = (gn < 512) ? (wih_f + (size_t)gn * cD)
                                           : (wih_b + (size_t)(gn - 512) * cD);
            float4 b4 = *(const float4*)(wrow + k0 + c);
            Bs[c + 0][n] = b4.x; Bs[c + 1][n] = b4.y; Bs[c + 2][n] = b4.z; Bs[c + 3][n] = b4.w;
        }
        __syncthreads();
#pragma unroll
        for (int k = 0; k < 16; ++k) {
            float a[4], bb[4];
#pragma unroll
            for (int i = 0; i < 4; ++i) a[i] = As[ty * 4 + i][k];
#pragma unroll
            for (int j = 0; j < 4; ++j) bb[j] = Bs[k][tx * 4 + j];
#pragma unroll
            for (int i = 0; i < 4; ++i)
#pragma unroll
                for (int j = 0; j < 4; ++j) acc[i][j] += a[i] * bb[j];
        }
        __syncthreads();
    }
#pragma unroll
    for (int i = 0; i < 4; ++i) {
        int m = m0 + ty * 4 + i;
#pragma unroll
        for (int j = 0; j < 4; ++j) {
            int n = n0 + tx * 4 + j;
            float bias = (n < 512) ? (bih_f[n] + bhh_f[n]) : (bih_b[n - 512] + bhh_b[n - 512]);
            pre[(size_t)m * 1024 + n] = acc[i][j] + bias;
        }
    }
}

// ---------------------------------------------------------------------------
// 3) MFMA LSTM. 4 blocks = (dir, bhalf); 256 thr = 4 waves.
//    Per step: gates(16b x 512n) = h(16b x 128k) @ Whh^T via mfma_16x16x32_bf16.
//    Whh lives in VGPRs as B-fragments (bf16). Wave w owns n-tiles {w,w+4,..,w+28}
//    -> i/f/g/o for a given (b,h) land in the SAME lane -> nonlinearity lane-local.
//    h exchanged via 2x4KB swizzled LDS ping-pong; one barrier per step.
__device__ __forceinline__ void pre_load(f32x4 (&dst)[8], int g, int bg, int lk4,
                                         int dsel, int w16, int lc,
                                         const float* __restrict__ pre) {
#pragma unroll
    for (int ni = 0; ni < 8; ++ni) {
        const float* pb = pre + (size_t)(g * 32 + bg + lk4) * 1024 + dsel + w16 + ni * 64 + lc;
#pragma unroll
        for (int r = 0; r < 4; ++r) dst[ni][r] = pb[(size_t)r * 1024];
    }
}

__device__ __forceinline__ void lstm_step(
    f32x4 (&cur)[8], f32x4 (&nxt)[8], float (&cst)[2][4], const bf16x8 (&wf)[8][4],
    unsigned short (*hlds)[2048], int s, bool dopre, bool domfma,
    int dir, int bg, int w16, int lc, int lk, int lk4, int dsel, int dsel4,
    const float* __restrict__ pre, float* __restrict__ h_out) {
    int g = dir ? (63 - s) : s;
    if (dopre) pre_load(nxt, dir ? (62 - s) : (s + 1), bg, lk4, dsel, w16, lc, pre);
    if (domfma) {
        const char* hb = (const char*)hlds[(s - 1) & 1];
#pragma unroll
        for (int kf = 0; kf < 4; ++kf) {
            bf16x8 a = *(const bf16x8*)(hb + ((lc * 256 + kf * 64 + lk * 16) ^ ((lc & 7) << 4)));
#pragma unroll
            for (int ni = 0; ni < 8; ++ni) cur[ni] = mfma16(a, wf[ni][kf], cur[ni]);
        }
    }
    char* hw = (char*)hlds[s & 1];
#pragma unroll
    for (int hi = 0; hi < 2; ++hi) {
#pragma unroll
        for (int r = 0; r < 4; ++r) {
            float ig = fsig(cur[0 + hi][r]);
            float fg = fsig(cur[2 + hi][r]);
            float gg = ftanh(cur[4 + hi][r]);
            float og = fsig(cur[6 + hi][r]);
            float cv = fg * cst[hi][r] + ig * gg;
            cst[hi][r] = cv;
            float hv = og * ftanh(cv);
            int b_ = lk4 + r;
            int h_ = w16 + hi * 64 + lc;
            *(__bf16*)(hw + ((b_ * 256 + h_ * 2) ^ ((b_ & 7) << 4))) = (__bf16)hv;
            h_out[((size_t)(bg + b_) * 64 + g) * 256 + dsel4 + h_] = hv;
        }
    }
}

__global__ __launch_bounds__(256, 1) void k_lstm_m(
    const float* __restrict__ pre,
    const float* __restrict__ whh_f, const float* __restrict__ whh_b,
    float* __restrict__ h_out) {
    __shared__ __align__(16) unsigned short hlds[2][2048];
    int t = threadIdx.x;
    int w = t >> 6, l = t & 63, lc = l & 15, lk = l >> 4;
    int dir = blockIdx.x >> 1, bg = (blockIdx.x & 1) * 16;
    int w16 = w * 16, lk4 = lk * 4, dsel = dir * 512, dsel4 = dir * 128;
    const float* whh = dir ? whh_b : whh_f;
    // B-fragments: wave w owns n-tiles {w + 4*ni}: n = w*16 + ni*64 + lc
    bf16x8 wf[8][4];
#pragma unroll
    for (int ni = 0; ni < 8; ++ni) {
        int n = w16 + ni * 64 + lc;
#pragma unroll
        for (int kf = 0; kf < 4; ++kf) {
            const float* src = whh + (size_t)n * 128 + kf * 32 + lk * 8;
            float4 s0 = *(const float4*)src, s1 = *(const float4*)(src + 4);
            bf16x8 v;
            v[0] = (__bf16)s0.x; v[1] = (__bf16)s0.y; v[2] = (__bf16)s0.z; v[3] = (__bf16)s0.w;
            v[4] = (__bf16)s1.x; v[5] = (__bf16)s1.y; v[6] = (__bf16)s1.z; v[7] = (__bf16)s1.w;
            wf[ni][kf] = v;
        }
    }
    f32x4 accE[8], accO[8];
    float cst[2][4] = {};
    int g0 = dir ? 63 : 0, g1 = dir ? 62 : 1;
    pre_load(accE, g0, bg, lk4, dsel, w16, lc, pre);
    pre_load(accO, g1, bg, lk4, dsel, w16, lc, pre);
    // step 0: gates = pre (h=0), no MFMA
    lstm_step(accE, accO, cst, wf, hlds, 0, false, false,
              dir, bg, w16, lc, lk, lk4, dsel, dsel4, pre, h_out);
    __syncthreads();
    for (int s = 1; s < 63; s += 2) {
        lstm_step(accO, accE, cst, wf, hlds, s, true, true,
                  dir, bg, w16, lc, lk, lk4, dsel, dsel4, pre, h_out);
        __syncthreads();
        lstm_step(accE, accO, cst, wf, hlds, s + 1, true, true,
                  dir, bg, w16, lc, lk, lk4, dsel, dsel4, pre, h_out);
        __syncthreads();
    }
    lstm_step(accO, accE, cst, wf, hlds, 63, false, true,
              dir, bg, w16, lc, lk, lk4, dsel, dsel4, pre, h_out);
}

// ---------------------------------------------------------------------------
// 4) gather h_grp[b, p2g[b, idx[b,n,k]], :] summed over k -> hsum[(b*8+n)][256]
__global__ void k_gather(const int* __restrict__ idx, const int* __restrict__ p2g,
                         const float* __restrict__ h_out, float* __restrict__ hsum) {
    int bn = blockIdx.x;
    int b = bn >> 3;
    int t = threadIdx.x;
    float acc = 0.f;
    for (int k = 0; k < cK; ++k) {
        int l = idx[bn * cK + k];
        int g = p2g[b * cL + l];
        acc += h_out[(size_t)(b * cG + g) * cH + t];
    }
    hsum[(size_t)bn * cH + t] = acc;
}

// ---------------------------------------------------------------------------
// 5) per-node projection (src / dst selected by blockIdx.y)
__global__ __launch_bounds__(128) void k_proj(
    const float* __restrict__ hsum,
    const float* __restrict__ w_src, const float* __restrict__ b_src,
    const float* __restrict__ w_dst, const float* __restrict__ b_dst,
    float* __restrict__ s_raw, float* __restrict__ d_raw) {
    int n = blockIdx.x, which = blockIdx.y, t = threadIdx.x;
    __shared__ float xr[cH];
    xr[t] = hsum[(size_t)n * cH + t];
    xr[t + 128] = hsum[(size_t)n * cH + t + 128];
    __syncthreads();
    const float* w = which ? w_dst : w_src;
    const float* bb = which ? b_dst : b_src;
    const float* wr = w + (size_t)t * cH;
    float acc = bb[t];
#pragma unroll 8
    for (int k = 0; k < cH; k += 4) {
        float4 w4 = *(const float4*)(wr + k);
        acc += w4.x * xr[k] + w4.y * xr[k + 1] + w4.z * xr[k + 2] + w4.w * xr[k + 3];
    }
    (which ? d_raw : s_raw)[(size_t)n * cNI + t] = acc;
}

// ---------------------------------------------------------------------------
// 6) BatchNorm over the 256 nodes (== BN over E, each node appears 8x)
__global__ void k_bn_nodes(const float* __restrict__ s_raw, const float* __restrict__ d_raw,
                           const float* __restrict__ g_src, const float* __restrict__ b_src,
                           const float* __restrict__ g_dst, const float* __restrict__ b_dst,
                           float* __restrict__ hd_bn, float* __restrict__ tl_bn) {
    int ch = blockIdx.x, which = ch >> 7, cc = ch & 127;
    int t = threadIdx.x;
    const float* raw = which ? d_raw : s_raw;
    float v = raw[(size_t)t * cNI + cc];
    __shared__ float ssum[256], ssq[256];
    ssum[t] = v;
    ssq[t] = v * v;
    __syncthreads();
    for (int o = 128; o > 0; o >>= 1) {
        if (t < o) { ssum[t] += ssum[t + o]; ssq[t] += ssq[t + o]; }
        __syncthreads();
    }
    float mean = ssum[0] * (1.f / 256.f);
    float var = ssq[0] * (1.f / 256.f) - mean * mean;
    float gam = which ? g_dst[cc] : g_src[cc];
    float bet = which ? b_dst[cc] : b_src[cc];
    float scale = gam * rsqrtf(var + cEPS);
    (which ? tl_bn : hd_bn)[(size_t)t * cNI + cc] = (v - mean) * scale + bet;
}

// ---------------------------------------------------------------------------
// 7) linear part of NTL per node: Lsrc[rh][n], Ldst[rh][n]
__global__ void k_lin(const float* __restrict__ ntl_v,
                      const float* __restrict__ hd_bn, const float* __restrict__ tl_bn,
                      float* __restrict__ lsrc, float* __restrict__ ldst) {
    int rh = blockIdx.x, t = threadIdx.x;
    __shared__ float vr[256];
    vr[t] = ntl_v[(size_t)rh * 256 + t];
    __syncthreads();
    const float* hr = hd_bn + (size_t)t * cNI;
    const float* tr = tl_bn + (size_t)t * cNI;
    float a1 = 0.f, a2 = 0.f;
#pragma unroll 8
    for (int i = 0; i < cNI; i += 4) {
        float4 h4 = *(const float4*)(hr + i);
        float4 t4 = *(const float4*)(tr + i);
        a1 += h4.x * vr[i] + h4.y * vr[i + 1] + h4.z * vr[i + 2] + h4.w * vr[i + 3];
        a2 += t4.x * vr[128 + i] + t4.y * vr[128 + i + 1] + t4.z * vr[128 + i + 2] + t4.w * vr[128 + i + 3];
    }
    lsrc[(size_t)rh * 256 + t] = a1;
    ldst[(size_t)rh * 256 + t] = a2;
}

// ---------------------------------------------------------------------------
// 8) MFMA NTL-A: tmp_frag[rh] = hd_bn(256x128) @ W[rh](128x128), bf16 frag-dump.
//    Element (m,j) of tile set: tmp[rh*32768 + (((w*4+mt)*8+nt)*64 + lane)*4 + r]
//    with m = w*64+mt*16+(lane>>4)*4+r, j = nt*16+(lane&15).
__global__ __launch_bounds__(256, 2) void k_ntl_A(
    const float* __restrict__ hd_bn, const float* __restrict__ ntl_w,
    unsigned short* __restrict__ tmp) {
    __shared__ __align__(16) unsigned short wl[128 * 128];  // swizzled bf16 W, 32KB
    int rh = blockIdx.x, t = threadIdx.x;
    int w = t >> 6, l = t & 63, lc = l & 15, lk = l >> 4;
    {
        const float* wbase = ntl_w + (size_t)rh * 16384;
        int k = t >> 1, c0 = (t & 1) * 64;
        int sw = ((k >> 3) & 3) << 4;
#pragma unroll
        for (int u = 0; u < 8; ++u) {
            const float* src = wbase + k * 128 + c0 + u * 8;
            float4 f0 = *(const float4*)src, f1 = *(const float4*)(src + 4);
            bf16x8 v;
            v[0] = (__bf16)f0.x; v[1] = (__bf16)f0.y; v[2] = (__bf16)f0.z; v[3] = (__bf16)f0.w;
            v[4] = (__bf16)f1.x; v[5] = (__bf16)f1.y; v[6] = (__bf16)f1.z; v[7] = (__bf16)f1.w;
            *(bf16x8*)((char*)wl + ((k * 256 + (c0 + u * 8) * 2) ^ sw)) = v;
        }
    }
    __syncthreads();
    f32x4 acc[4][8] = {};
#pragma unroll
    for (int kf = 0; kf < 4; ++kf) {
        bf16x8 af[4];
#pragma unroll
        for (int mt = 0; mt < 4; ++mt) {
            int m = w * 64 + mt * 16 + lc;
            const float* ap = hd_bn + (size_t)m * 128 + kf * 32 + lk * 8;
            float4 a0 = *(const float4*)ap, a1 = *(const float4*)(ap + 4);
            bf16x8 v;
            v[0] = (__bf16)a0.x; v[1] = (__bf16)a0.y; v[2] = (__bf16)a0.z; v[3] = (__bf16)a0.w;
            v[4] = (__bf16)a1.x; v[5] = (__bf16)a1.y; v[6] = (__bf16)a1.z; v[7] = (__bf16)a1.w;
            af[mt] = v;
        }
#pragma unroll
        for (int nt = 0; nt < 8; ++nt) {
            int kb = (kf * 32 + lk * 8) * 256;
            int jb = (nt * 16 + lc) * 2;
            bf16x8 bv = *(const bf16x8*)((char*)wl + ((kb + jb) ^ (lk << 4)));
#pragma unroll
            for (int mt = 0; mt < 4; ++mt) acc[mt][nt] = mfma16(af[mt], bv, acc[mt][nt]);
        }
    }
#pragma unroll
    for (int mt = 0; mt < 4; ++mt) {
#pragma unroll
        for (int nt = 0; nt < 8; ++nt) {
            unsigned int lo = (unsigned int)f2bf(acc[mt][nt][0]) | ((unsigned int)f2bf(acc[mt][nt][1]) << 16);
            unsigned int hi = (unsigned int)f2bf(acc[mt][nt][2]) | ((unsigned int)f2bf(acc[mt][nt][3]) << 16);
            size_t off = (size_t)rh * 32768 + (size_t)((((w * 4 + mt) * 8 + nt) * 64 + l) * 4);
            *(uint2*)(tmp + off) = make_uint2(lo, hi);
        }
    }
}

// ---------------------------------------------------------------------------
// 9) bilinear dot + linear + bias -> pre2[rh][e]; decodes frag-dump tmp.
__global__ __launch_bounds__(256) void k_ntl_B(
    const unsigned short* __restrict__ tmp, const float* __restrict__ tl_bn,
    const float* __restrict__ lsrc, const float* __restrict__ ldst,
    const float* __restrict__ ntl_b, float* __restrict__ pre2) {
    int bgid = blockIdx.x;  // 0..7 (32-node slice)
    int rh = blockIdx.y;
    int t = threadIdx.x;
    int n0 = bgid * 32;
    __shared__ float tm[32][132];
    __shared__ float tl[32][132];
    {
        // decode frag-dump slice: wave w' = bgid>>1, mt pair = bgid&1
        const uint4* src = (const uint4*)(tmp + (size_t)rh * 32768 +
                                          (size_t)(bgid >> 1) * 8192 + (size_t)(bgid & 1) * 4096);
#pragma unroll
        for (int rep = 0; rep < 2; ++rep) {
            int q = t + rep * 256;
            uint4 uv = src[q];
            unsigned int wds[4] = {uv.x, uv.y, uv.z, uv.w};
            int e0 = q * 8;
#pragma unroll
            for (int ui = 0; ui < 4; ++ui) {
                int e = e0 + ui * 2;
                int mt_l = e >> 11;
                int nt = (e >> 8) & 7;
                int ln = (e >> 2) & 63;
                int r = e & 3;
                int m = mt_l * 16 + (ln >> 4) * 4 + r;
                int j = nt * 16 + (ln & 15);
                tm[m][j] = bf2f((unsigned short)(wds[ui] & 0xffff));
                tm[m + 1][j] = bf2f((unsigned short)(wds[ui] >> 16));
            }
        }
        int r = t >> 3;
        int c0 = (t & 7) * 16;
        const float4* fsrc = (const float4*)(tl_bn + (size_t)(n0 + r) * cNI + c0);
        float4 f0 = fsrc[0], f1 = fsrc[1], f2v = fsrc[2], f3 = fsrc[3];
        float* frow = &tl[r][c0];
        frow[0] = f0.x; frow[1] = f0.y; frow[2] = f0.z; frow[3] = f0.w;
        frow[4] = f1.x; frow[5] = f1.y; frow[6] = f1.z; frow[7] = f1.w;
        frow[8] = f2v.x; frow[9] = f2v.y; frow[10] = f2v.z; frow[11] = f2v.w;
        frow[12] = f3.x; frow[13] = f3.y; frow[14] = f3.z; frow[15] = f3.w;
    }
    __syncthreads();
    int b_l = t >> 6, p = t & 63, i = p >> 3, j = p & 7;
    const float* ta = &tm[b_l * 8 + i][0];
    const float* tb = &tl[b_l * 8 + j][0];
    float s = 0.f;
#pragma unroll 8
    for (int k = 0; k < 128; ++k) s += ta[k] * tb[k];
    int e = bgid * 256 + t;
    int bglob = bgid * 4 + b_l;
    int un = bglob * 8 + i, vn = bglob * 8 + j;
    pre2[(size_t)rh * cE + e] = s + lsrc[(size_t)rh * 256 + un] + ldst[(size_t)rh * 256 + vn] + ntl_b[rh];
}

// ---------------------------------------------------------------------------
// 10) BN stats over E per rh channel -> scale/shift
__global__ void k_bn2(const float* __restrict__ pre2,
                      const float* __restrict__ g, const float* __restrict__ bta,
                      float* __restrict__ scale, float* __restrict__ shift) {
    int rh = blockIdx.x, t = threadIdx.x;
    const float* row = pre2 + (size_t)rh * cE;
    float s = 0.f, q = 0.f;
#pragma unroll
    for (int ii = 0; ii < 8; ++ii) {
        float v = row[ii * 256 + t];
        s += v; q += v * v;
    }
    __shared__ float ssum[256], ssq[256];
    ssum[t] = s; ssq[t] = q;
    __syncthreads();
    for (int o = 128; o > 0; o >>= 1) {
        if (t < o) { ssum[t] += ssum[t + o]; ssq[t] += ssq[t + o]; }
        __syncthreads();
    }
    if (t == 0) {
        float mean = ssum[0] * (1.f / 2048.f);
        float var = ssq[0] * (1.f / 2048.f) - mean * mean;
        float sc = g[rh] * rsqrtf(var + cEPS);
        scale[rh] = sc;
        shift[rh] = bta[rh] - mean * sc;
    }
}

// ---------------------------------------------------------------------------
// 11) logit[e][r] = sum_h u[r*32+h] * tanh(pre2*scale+shift); grid (8 e-tiles, 16 r)
__global__ __launch_bounds__(256) void k_final(
    const float* __restrict__ pre2,
    const float* __restrict__ scale, const float* __restrict__ shift,
    const float* __restrict__ ntl_u, float* __restrict__ out) {
    int r = blockIdx.y;
    int e = blockIdx.x * 256 + threadIdx.x;
    float a = 0.f;
#pragma unroll
    for (int h = 0; h < 32; ++h) {
        int rh = r * 32 + h;
        float p = pre2[(size_t)rh * cE + e];
        a += ntl_u[rh] * ftanh(fmaf(p, scale[rh], shift[rh]));
    }
    out[(size_t)e * 16 + r] = a;
}

// ---------------------------------------------------------------------------
// 12) per-graph loss/acc/em partials
__global__ void k_loss(const float* __restrict__ out, const int* __restrict__ mask,
                       float* __restrict__ part) {
    int b = blockIdx.x, t = threadIdx.x;
    float nll = 0.f;
    int corr = 0, em = 1;
#pragma unroll
    for (int q = 0; q < 4; ++q) {
        int f = t * 4 + q;
        float x = out[(size_t)b * 1024 + f];
        int m = mask[(size_t)b * 1024 + f];
        bool gt = x > 0.f;
        bool mb = (m != 0);
        bool eq = (gt == mb);
        corr += eq ? 1 : 0;
        em &= eq ? 1 : 0;
        if (mb) nll += nls(x);
        else nll += -logf(1.f / (1.f + expf(x)) + 1e-5f);
    }
    __shared__ float rs[256];
    __shared__ int rc[256], re[256];
    rs[t] = nll; rc[t] = corr; re[t] = em;
    __syncthreads();
    for (int o = 128; o > 0; o >>= 1) {
        if (t < o) { rs[t] += rs[t + o]; rc[t] += rc[t + o]; re[t] &= re[t + o]; }
        __syncthreads();
    }
    if (t == 0) {
        part[b * 4 + 0] = rs[0];
        part[b * 4 + 1] = (float)rc[0];
        part[b * 4 + 2] = (float)re[0];
    }
}

__global__ void k_loss_fin(const float* __restrict__ part, float* __restrict__ out) {
    if (threadIdx.x == 0) {
        float nll = 0.f, corr = 0.f, em = 0.f;
        for (int b = 0; b < 32; ++b) {
            nll += part[b * 4 + 0];
            corr += part[b * 4 + 1];
            em += part[b * 4 + 2];
        }
        out[32768] = nll / 32.f;
        out[32769] = corr / 32768.f;
        out[32770] = em / 32.f;
    }
}

}  // namespace

extern "C" void kernel_launch(void* const* d_in, const int* in_sizes, int n_in,
                              void* d_out, int out_size, void* d_ws, size_t ws_size,
                              hipStream_t stream) {
    (void)in_sizes; (void)n_in; (void)out_size; (void)ws_size;
    const int* seq = (const int*)d_in[0];
    const int* p2g = (const int*)d_in[1];
    const int* idx = (const int*)d_in[2];
    const int* mask = (const int*)d_in[5];
    const float* emb = (const float*)d_in[6];
    const float* wih_f = (const float*)d_in[7];
    const float* whh_f = (const float*)d_in[8];
    const float* bih_f = (const float*)d_in[9];
    const float* bhh_f = (const float*)d_in[10];
    const float* wih_b = (const float*)d_in[11];
    const float* whh_b = (const float*)d_in[12];
    const float* bih_b = (const float*)d_in[13];
    const float* bhh_b = (const float*)d_in[14];
    const float* lsw = (const float*)d_in[15];
    const float* lsb = (const float*)d_in[16];
    const float* ldw = (const float*)d_in[17];
    const float* ldb = (const float*)d_in[18];
    const float* bn_sg = (const float*)d_in[19];
    const float* bn_sb = (const float*)d_in[20];
    const float* bn_dg = (const float*)d_in[21];
    const float* bn_db = (const float*)d_in[22];
    const float* ntlw = (const float*)d_in[23];
    const float* ntlv = (const float*)d_in[24];
    const float* ntlb = (const float*)d_in[25];
    const float* ntlu = (const float*)d_in[26];
    const float* bn2g = (const float*)d_in[27];
    const float* bn2b = (const float*)d_in[28];
    float* out = (float*)d_out;
    char* ws = (char*)d_ws;

    float* x_seq = (float*)(ws + 0);
    float* pre = (float*)(ws + 2097152);
    unsigned short* tmp = (unsigned short*)(ws + 0);
    size_t off = 33554432;
    float* h_out = (float*)(ws + off); off += 2097152;
    float* hsum = (float*)(ws + off); off += 262144;
    float* s_raw = (float*)(ws + off); off += 131072;
    float* d_raw = (float*)(ws + off); off += 131072;
    float* hd_bn = (float*)(ws + off); off += 131072;
    float* tl_bn = (float*)(ws + off); off += 131072;
    float* lsrc = (float*)(ws + off); off += 524288;
    float* ldst = (float*)(ws + off); off += 524288;
    float* pre2 = (float*)(ws + off); off += 4194304;
    float* scale = (float*)(ws + off); off += 2048;
    float* shift = (float*)(ws + off); off += 2048;
    float* part = (float*)(ws + off); off += 512;

    k_embed<<<32, 256, 0, stream>>>(seq, p2g, emb, x_seq);
    k_gemm_in<<<dim3(16, 32), 256, 0, stream>>>(x_seq, wih_f, wih_b, bih_f, bhh_f, bih_b, bhh_b, pre);
    k_lstm_m<<<4, 256, 0, stream>>>(pre, whh_f, whh_b, h_out);
    k_gather<<<256, 256, 0, stream>>>(idx, p2g, h_out, hsum);
    k_proj<<<dim3(256, 2), 128, 0, stream>>>(hsum, lsw, lsb, ldw, ldb, s_raw, d_raw);
    k_bn_nodes<<<256, 256, 0, stream>>>(s_raw, d_raw, bn_sg, bn_sb, bn_dg, bn_db, hd_bn, tl_bn);
    k_lin<<<512, 256, 0, stream>>>(ntlv, hd_bn, tl_bn, lsrc, ldst);
    k_ntl_A<<<512, 256, 0, stream>>>(hd_bn, ntlw, tmp);
    k_ntl_B<<<dim3(8, 512), 256, 0, stream>>>(tmp, tl_bn, lsrc, ldst, ntlb, pre2);
    k_bn2<<<512, 256, 0, stream>>>(pre2, bn2g, bn2b, scale, shift);
    k_final<<<dim3(8, 16), 256, 0, stream>>>(pre2, scale, shift, ntlu, out);
    k_loss<<<32, 256, 0, stream>>>(out, mask, part);
    k_loss_fin<<<1, 32, 0, stream>>>(part, out);
}

// Round 4
// 232.531 us; speedup vs baseline: 1.1606x; 1.1606x over previous
//
#include <hip/hip_runtime.h>
#include <math.h>

namespace {

constexpr int cB = 32, cL = 128, cG = 64, cD = 256;
constexpr int cHD = 128, cH = 256;
constexpr int cN = 8, cK = 4;
constexpr int cNI = 128, cRH = 512;
constexpr int cE = 2048;
constexpr float cEPS = 1e-5f;

typedef __bf16 bf16x8 __attribute__((ext_vector_type(8)));
typedef float f32x4 __attribute__((ext_vector_type(4)));

__device__ __forceinline__ f32x4 mfma16(bf16x8 a, bf16x8 b, f32x4 c) {
    return __builtin_amdgcn_mfma_f32_16x16x32_bf16(a, b, c, 0, 0, 0);
}

__device__ __forceinline__ float bf2f(unsigned short u) {
    unsigned int x = ((unsigned int)u) << 16;
    return __uint_as_float(x);
}
__device__ __forceinline__ unsigned short f2bf(float f) {
    unsigned int x = __float_as_uint(f);
    unsigned int r = (x + 0x7fffu + ((x >> 16) & 1u)) >> 16;  // RNE
    return (unsigned short)r;
}
__device__ __forceinline__ float fsig(float x) { return 1.f / (1.f + __expf(-x)); }
__device__ __forceinline__ float ftanh(float x) { return 1.f - 2.f / (__expf(2.f * x) + 1.f); }
__device__ __forceinline__ float nls(float x) {
    return (x >= 0.f) ? log1pf(expf(-x)) : (log1pf(expf(x)) - x);
}

// lgkm-only barrier: LDS ping-pong needs lgkmcnt ordering, NOT a vmcnt(0) drain.
// (__syncthreads makes the compiler drain vmcnt(0), serializing our prefetches.)
__device__ __forceinline__ void bar_lgkm() {
    asm volatile("s_waitcnt lgkmcnt(0)\n\ts_barrier" ::: "memory");
}

// ---------------------------------------------------------------------------
// 1) token embedding + scatter_sum into groups, output layout (g, b, d)
__global__ void k_embed(const int* __restrict__ seq, const int* __restrict__ p2g,
                        const float* __restrict__ emb, float* __restrict__ x_seq) {
    __shared__ float xl[cG * cD];
    int b = blockIdx.x, t = threadIdx.x;
    for (int g = 0; g < cG; ++g) xl[g * cD + t] = 0.f;
    for (int l = 0; l < cL; ++l) {
        int tok = seq[b * cL + l];
        int g = p2g[b * cL + l];
        xl[g * cD + t] += emb[tok * cD + t];
    }
    for (int g = 0; g < cG; ++g)
        x_seq[(g * cB + b) * cD + t] = xl[g * cD + t];
}

// ---------------------------------------------------------------------------
// 2) LSTM input GEMM: pre[(g*32+b)][n] = x_seq row . Wcat[n] + bih+bhh
__global__ __launch_bounds__(256) void k_gemm_in(
    const float* __restrict__ x_seq,
    const float* __restrict__ wih_f, const float* __restrict__ wih_b,
    const float* __restrict__ bih_f, const float* __restrict__ bhh_f,
    const float* __restrict__ bih_b, const float* __restrict__ bhh_b,
    float* __restrict__ pre) {
    __shared__ float As[64][17];
    __shared__ float Bs[16][68];
    int t = threadIdx.x;
    int n0 = blockIdx.x * 64, m0 = blockIdx.y * 64;
    int tx = t & 15, ty = t >> 4;
    float acc[4][4] = {};
    for (int k0 = 0; k0 < cD; k0 += 16) {
        {
            int r = t >> 2, c = (t & 3) * 4;
            float4 a4 = *(const float4*)(x_seq + (size_t)(m0 + r) * cD + k0 + c);
            As[r][c + 0] = a4.x; As[r][c + 1] = a4.y; As[r][c + 2] = a4.z; As[r][c + 3] = a4.w;
        }
        {
            int n = t >> 2, c = (t & 3) * 4;
            int gn = n0 + n;
            const float* wrow = (gn < 512) ? (wih_f + (size_t)gn * cD)
                                           : (wih_b + (size_t)(gn - 512) * cD);
            float4 b4 = *(const float4*)(wrow + k0 + c);
            Bs[c + 0][n] = b4.x; Bs[c + 1][n] = b4.y; Bs[c + 2][n] = b4.z; Bs[c + 3][n] = b4.w;
        }
        __syncthreads();
#pragma unroll
        for (int k = 0; k < 16; ++k) {
            float a[4], bb[4];
#pragma unroll
            for (int i = 0; i < 4; ++i) a[i] = As[ty * 4 + i][k];
#pragma unroll
            for (int j = 0; j < 4; ++j) bb[j] = Bs[k][tx * 4 + j];
#pragma unroll
            for (int i = 0; i < 4; ++i)
#pragma unroll
                for (int j = 0; j < 4; ++j) acc[i][j] += a[i] * bb[j];
        }
        __syncthreads();
    }
#pragma unroll
    for (int i = 0; i < 4; ++i) {
        int m = m0 + ty * 4 + i;
#pragma unroll
        for (int j = 0; j < 4; ++j) {
            int n = n0 + tx * 4 + j;
            float bias = (n < 512) ? (bih_f[n] + bhh_f[n]) : (bih_b[n - 512] + bhh_b[n - 512]);
            pre[(size_t)m * 1024 + n] = acc[i][j] + bias;
        }
    }
}

// ---------------------------------------------------------------------------
// 3) MFMA LSTM v2. 4 blocks = (dir, bhalf); 512 thr = 8 waves (2/SIMD).
//    Wave w owns h-block [w*16, w*16+16); its 4 MFMA tiles q = gates i,f,g,o.
//    A = Whh fragments stationary in VGPRs (bf16, 64 VGPR/lane).
//    B = h(t-1) from 4KB swizzled LDS ping-pong (4x ds_read_b128/lane).
//    D: row=(lk*4+r)=n-in-tile, col=lc=batch -> 4 consecutive n per lane:
//      pre init = 4x global_load_dwordx4, h store = 1x ds_write_b64 + 1x dwordx4.
//    Hand lgkm-barrier per step; pre(s+2) prefetched into acc after consumption.
__device__ __forceinline__ void lstm_step(
    f32x4 (&acc)[4], float (&cst)[4], const bf16x8 (&wf)[4][4],
    const unsigned short* __restrict__ hr, unsigned short* __restrict__ hw,
    const int (&rdo)[4], int wro,
    const float* __restrict__ preb, int gpre, bool dopre,
    float* __restrict__ hob, int g) {
    bf16x8 hf[4];
#pragma unroll
    for (int kf = 0; kf < 4; ++kf)
        hf[kf] = *(const bf16x8*)((const char*)hr + rdo[kf]);
#pragma unroll
    for (int kf = 0; kf < 4; ++kf)
#pragma unroll
        for (int q = 0; q < 4; ++q)
            acc[q] = mfma16(wf[q][kf], hf[kf], acc[q]);
    float hv[4];
#pragma unroll
    for (int r = 0; r < 4; ++r) {
        float ig = fsig(acc[0][r]);
        float fg = fsig(acc[1][r]);
        float gg = ftanh(acc[2][r]);
        float og = fsig(acc[3][r]);
        float cv = fg * cst[r] + ig * gg;
        cst[r] = cv;
        hv[r] = og * ftanh(cv);
    }
    if (dopre) {
#pragma unroll
        for (int q = 0; q < 4; ++q)
            acc[q] = *(const f32x4*)(preb + (size_t)gpre * 32768 + q * 128);
    }
    unsigned int p0 = (unsigned int)f2bf(hv[0]) | ((unsigned int)f2bf(hv[1]) << 16);
    unsigned int p1 = (unsigned int)f2bf(hv[2]) | ((unsigned int)f2bf(hv[3]) << 16);
    *(uint2*)((char*)hw + wro) = make_uint2(p0, p1);
    *(float4*)(hob + (size_t)g * 256) = make_float4(hv[0], hv[1], hv[2], hv[3]);
    bar_lgkm();
}

__global__ __launch_bounds__(512, 2) void k_lstm_m(
    const float* __restrict__ pre,
    const float* __restrict__ whh_f, const float* __restrict__ whh_b,
    float* __restrict__ h_out) {
    __shared__ __align__(16) unsigned short hl[2][2048];  // [buf][b(16) x h(128)] bf16
    int t = threadIdx.x;
    int w = t >> 6, l = t & 63, lc = l & 15, lk = l >> 4;
    int dir = blockIdx.x >> 1, bg = (blockIdx.x & 1) * 16;
    const float* whh = dir ? whh_b : whh_f;
    // stationary A-fragments: wave w, tile q -> Whh rows n = q*128 + w*16 + lc
    bf16x8 wf[4][4];
#pragma unroll
    for (int q = 0; q < 4; ++q) {
        int n = q * 128 + w * 16 + lc;
#pragma unroll
        for (int kf = 0; kf < 4; ++kf) {
            const float* src = whh + (size_t)n * 128 + kf * 32 + lk * 8;
            float4 s0 = *(const float4*)src, s1 = *(const float4*)(src + 4);
            bf16x8 v;
            v[0] = (__bf16)s0.x; v[1] = (__bf16)s0.y; v[2] = (__bf16)s0.z; v[3] = (__bf16)s0.w;
            v[4] = (__bf16)s1.x; v[5] = (__bf16)s1.y; v[6] = (__bf16)s1.z; v[7] = (__bf16)s1.w;
            wf[q][kf] = v;
        }
    }
    // zero h(-1) buffer (hl[1]): 512 threads x 8B = 4KB
    *(uint2*)&hl[1][t * 4] = make_uint2(0u, 0u);
    // per-lane bases
    const float* preb = pre + (size_t)(bg + lc) * 1024 + dir * 512 + w * 16 + lk * 4;
    float* hob = (float*)0;
    {
        size_t o = ((size_t)(bg + lc) * 64) * 256 + dir * 128 + w * 16 + lk * 4;
        hob = (float*)((char*)0);  // placeholder, set below
    }
    int rdo[4];
#pragma unroll
    for (int kf = 0; kf < 4; ++kf)
        rdo[kf] = (lc * 256 + kf * 64 + lk * 16) ^ ((lc & 7) << 4);
    int wro = (lc * 256 + w * 32 + lk * 8) ^ ((lc & 7) << 4);
    f32x4 accA[4], accB[4];
    float cst[4] = {0.f, 0.f, 0.f, 0.f};
    int g0 = dir ? 63 : 0;
    int sgn = dir ? -1 : 1;
#pragma unroll
    for (int q = 0; q < 4; ++q) accA[q] = *(const f32x4*)(preb + (size_t)g0 * 32768 + q * 128);
#pragma unroll
    for (int q = 0; q < 4; ++q) accB[q] = *(const f32x4*)(preb + (size_t)(g0 + sgn) * 32768 + q * 128);
    bar_lgkm();  // zero-init visible
    for (int s = 0; s < 64; s += 2) {
        int ga = g0 + sgn * s;
        lstm_step(accA, cst, wf, hl[1], hl[0], rdo, wro, preb,
                  ga + 2 * sgn, s < 62, h_out + ((size_t)(bg + lc) * 64) * 256 + dir * 128 + w * 16 + lk * 4, ga);
        lstm_step(accB, cst, wf, hl[0], hl[1], rdo, wro, preb,
                  ga + 3 * sgn, s < 61, h_out + ((size_t)(bg + lc) * 64) * 256 + dir * 128 + w * 16 + lk * 4, ga + sgn);
    }
}

// ---------------------------------------------------------------------------
// 4) gather h_grp[b, p2g[b, idx[b,n,k]], :] summed over k -> hsum[(b*8+n)][256]
__global__ void k_gather(const int* __restrict__ idx, const int* __restrict__ p2g,
                         const float* __restrict__ h_out, float* __restrict__ hsum) {
    int bn = blockIdx.x;
    int b = bn >> 3;
    int t = threadIdx.x;
    float acc = 0.f;
    for (int k = 0; k < cK; ++k) {
        int l = idx[bn * cK + k];
        int g = p2g[b * cL + l];
        acc += h_out[(size_t)(b * cG + g) * cH + t];
    }
    hsum[(size_t)bn * cH + t] = acc;
}

// ---------------------------------------------------------------------------
// 5) per-node projection (src / dst selected by blockIdx.y)
__global__ __launch_bounds__(128) void k_proj(
    const float* __restrict__ hsum,
    const float* __restrict__ w_src, const float* __restrict__ b_src,
    const float* __restrict__ w_dst, const float* __restrict__ b_dst,
    float* __restrict__ s_raw, float* __restrict__ d_raw) {
    int n = blockIdx.x, which = blockIdx.y, t = threadIdx.x;
    __shared__ float xr[cH];
    xr[t] = hsum[(size_t)n * cH + t];
    xr[t + 128] = hsum[(size_t)n * cH + t + 128];
    __syncthreads();
    const float* w = which ? w_dst : w_src;
    const float* bb = which ? b_dst : b_src;
    const float* wr = w + (size_t)t * cH;
    float acc = bb[t];
#pragma unroll 8
    for (int k = 0; k < cH; k += 4) {
        float4 w4 = *(const float4*)(wr + k);
        acc += w4.x * xr[k] + w4.y * xr[k + 1] + w4.z * xr[k + 2] + w4.w * xr[k + 3];
    }
    (which ? d_raw : s_raw)[(size_t)n * cNI + t] = acc;
}

// ---------------------------------------------------------------------------
// 6) BatchNorm over the 256 nodes (== BN over E, each node appears 8x)
__global__ void k_bn_nodes(const float* __restrict__ s_raw, const float* __restrict__ d_raw,
                           const float* __restrict__ g_src, const float* __restrict__ b_src,
                           const float* __restrict__ g_dst, const float* __restrict__ b_dst,
                           float* __restrict__ hd_bn, float* __restrict__ tl_bn) {
    int ch = blockIdx.x, which = ch >> 7, cc = ch & 127;
    int t = threadIdx.x;
    const float* raw = which ? d_raw : s_raw;
    float v = raw[(size_t)t * cNI + cc];
    __shared__ float ssum[256], ssq[256];
    ssum[t] = v;
    ssq[t] = v * v;
    __syncthreads();
    for (int o = 128; o > 0; o >>= 1) {
        if (t < o) { ssum[t] += ssum[t + o]; ssq[t] += ssq[t + o]; }
        __syncthreads();
    }
    float mean = ssum[0] * (1.f / 256.f);
    float var = ssq[0] * (1.f / 256.f) - mean * mean;
    float gam = which ? g_dst[cc] : g_src[cc];
    float bet = which ? b_dst[cc] : b_src[cc];
    float scale = gam * rsqrtf(var + cEPS);
    (which ? tl_bn : hd_bn)[(size_t)t * cNI + cc] = (v - mean) * scale + bet;
}

// ---------------------------------------------------------------------------
// 7) linear part of NTL per node: Lsrc[rh][n], Ldst[rh][n]
__global__ void k_lin(const float* __restrict__ ntl_v,
                      const float* __restrict__ hd_bn, const float* __restrict__ tl_bn,
                      float* __restrict__ lsrc, float* __restrict__ ldst) {
    int rh = blockIdx.x, t = threadIdx.x;
    __shared__ float vr[256];
    vr[t] = ntl_v[(size_t)rh * 256 + t];
    __syncthreads();
    const float* hr = hd_bn + (size_t)t * cNI;
    const float* tr = tl_bn + (size_t)t * cNI;
    float a1 = 0.f, a2 = 0.f;
#pragma unroll 8
    for (int i = 0; i < cNI; i += 4) {
        float4 h4 = *(const float4*)(hr + i);
        float4 t4 = *(const float4*)(tr + i);
        a1 += h4.x * vr[i] + h4.y * vr[i + 1] + h4.z * vr[i + 2] + h4.w * vr[i + 3];
        a2 += t4.x * vr[128 + i] + t4.y * vr[128 + i + 1] + t4.z * vr[128 + i + 2] + t4.w * vr[128 + i + 3];
    }
    lsrc[(size_t)rh * 256 + t] = a1;
    ldst[(size_t)rh * 256 + t] = a2;
}

// ---------------------------------------------------------------------------
// 8) MFMA NTL-A: tmp_frag[rh] = hd_bn(256x128) @ W[rh](128x128), bf16 frag-dump.
__global__ __launch_bounds__(256, 2) void k_ntl_A(
    const float* __restrict__ hd_bn, const float* __restrict__ ntl_w,
    unsigned short* __restrict__ tmp) {
    __shared__ __align__(16) unsigned short wl[128 * 128];
    int rh = blockIdx.x, t = threadIdx.x;
    int w = t >> 6, l = t & 63, lc = l & 15, lk = l >> 4;
    {
        const float* wbase = ntl_w + (size_t)rh * 16384;
        int k = t >> 1, c0 = (t & 1) * 64;
        int sw = ((k >> 3) & 3) << 4;
#pragma unroll
        for (int u = 0; u < 8; ++u) {
            const float* src = wbase + k * 128 + c0 + u * 8;
            float4 f0 = *(const float4*)src, f1 = *(const float4*)(src + 4);
            bf16x8 v;
            v[0] = (__bf16)f0.x; v[1] = (__bf16)f0.y; v[2] = (__bf16)f0.z; v[3] = (__bf16)f0.w;
            v[4] = (__bf16)f1.x; v[5] = (__bf16)f1.y; v[6] = (__bf16)f1.z; v[7] = (__bf16)f1.w;
            *(bf16x8*)((char*)wl + ((k * 256 + (c0 + u * 8) * 2) ^ sw)) = v;
        }
    }
    __syncthreads();
    f32x4 acc[4][8] = {};
#pragma unroll
    for (int kf = 0; kf < 4; ++kf) {
        bf16x8 af[4];
#pragma unroll
        for (int mt = 0; mt < 4; ++mt) {
            int m = w * 64 + mt * 16 + lc;
            const float* ap = hd_bn + (size_t)m * 128 + kf * 32 + lk * 8;
            float4 a0 = *(const float4*)ap, a1 = *(const float4*)(ap + 4);
            bf16x8 v;
            v[0] = (__bf16)a0.x; v[1] = (__bf16)a0.y; v[2] = (__bf16)a0.z; v[3] = (__bf16)a0.w;
            v[4] = (__bf16)a1.x; v[5] = (__bf16)a1.y; v[6] = (__bf16)a1.z; v[7] = (__bf16)a1.w;
            af[mt] = v;
        }
#pragma unroll
        for (int nt = 0; nt < 8; ++nt) {
            int kb = (kf * 32 + lk * 8) * 256;
            int jb = (nt * 16 + lc) * 2;
            bf16x8 bv = *(const bf16x8*)((char*)wl + ((kb + jb) ^ (lk << 4)));
#pragma unroll
            for (int mt = 0; mt < 4; ++mt) acc[mt][nt] = mfma16(af[mt], bv, acc[mt][nt]);
        }
    }
#pragma unroll
    for (int mt = 0; mt < 4; ++mt) {
#pragma unroll
        for (int nt = 0; nt < 8; ++nt) {
            unsigned int lo = (unsigned int)f2bf(acc[mt][nt][0]) | ((unsigned int)f2bf(acc[mt][nt][1]) << 16);
            unsigned int hi = (unsigned int)f2bf(acc[mt][nt][2]) | ((unsigned int)f2bf(acc[mt][nt][3]) << 16);
            size_t off = (size_t)rh * 32768 + (size_t)((((w * 4 + mt) * 8 + nt) * 64 + l) * 4);
            *(uint2*)(tmp + off) = make_uint2(lo, hi);
        }
    }
}

// ---------------------------------------------------------------------------
// 9) bilinear dot + linear + bias -> pre2[rh][e]; decodes frag-dump tmp.
__global__ __launch_bounds__(256) void k_ntl_B(
    const unsigned short* __restrict__ tmp, const float* __restrict__ tl_bn,
    const float* __restrict__ lsrc, const float* __restrict__ ldst,
    const float* __restrict__ ntl_b, float* __restrict__ pre2) {
    int bgid = blockIdx.x;
    int rh = blockIdx.y;
    int t = threadIdx.x;
    int n0 = bgid * 32;
    __shared__ float tm[32][132];
    __shared__ float tl[32][132];
    {
        const uint4* src = (const uint4*)(tmp + (size_t)rh * 32768 +
                                          (size_t)(bgid >> 1) * 8192 + (size_t)(bgid & 1) * 4096);
#pragma unroll
        for (int rep = 0; rep < 2; ++rep) {
            int q = t + rep * 256;
            uint4 uv = src[q];
            unsigned int wds[4] = {uv.x, uv.y, uv.z, uv.w};
            int e0 = q * 8;
#pragma unroll
            for (int ui = 0; ui < 4; ++ui) {
                int e = e0 + ui * 2;
                int mt_l = e >> 11;
                int nt = (e >> 8) & 7;
                int ln = (e >> 2) & 63;
                int r = e & 3;
                int m = mt_l * 16 + (ln >> 4) * 4 + r;
                int j = nt * 16 + (ln & 15);
                tm[m][j] = bf2f((unsigned short)(wds[ui] & 0xffff));
                tm[m + 1][j] = bf2f((unsigned short)(wds[ui] >> 16));
            }
        }
        int r = t >> 3;
        int c0 = (t & 7) * 16;
        const float4* fsrc = (const float4*)(tl_bn + (size_t)(n0 + r) * cNI + c0);
        float4 f0 = fsrc[0], f1 = fsrc[1], f2v = fsrc[2], f3 = fsrc[3];
        float* frow = &tl[r][c0];
        frow[0] = f0.x; frow[1] = f0.y; frow[2] = f0.z; frow[3] = f0.w;
        frow[4] = f1.x; frow[5] = f1.y; frow[6] = f1.z; frow[7] = f1.w;
        frow[8] = f2v.x; frow[9] = f2v.y; frow[10] = f2v.z; frow[11] = f2v.w;
        frow[12] = f3.x; frow[13] = f3.y; frow[14] = f3.z; frow[15] = f3.w;
    }
    __syncthreads();
    int b_l = t >> 6, p = t & 63, i = p >> 3, j = p & 7;
    const float* ta = &tm[b_l * 8 + i][0];
    const float* tb = &tl[b_l * 8 + j][0];
    float s = 0.f;
#pragma unroll 8
    for (int k = 0; k < 128; ++k) s += ta[k] * tb[k];
    int e = bgid * 256 + t;
    int bglob = bgid * 4 + b_l;
    int un = bglob * 8 + i, vn = bglob * 8 + j;
    pre2[(size_t)rh * cE + e] = s + lsrc[(size_t)rh * 256 + un] + ldst[(size_t)rh * 256 + vn] + ntl_b[rh];
}

// ---------------------------------------------------------------------------
// 10) BN stats over E per rh channel -> scale/shift
__global__ void k_bn2(const float* __restrict__ pre2,
                      const float* __restrict__ g, const float* __restrict__ bta,
                      float* __restrict__ scale, float* __restrict__ shift) {
    int rh = blockIdx.x, t = threadIdx.x;
    const float* row = pre2 + (size_t)rh * cE;
    float s = 0.f, q = 0.f;
#pragma unroll
    for (int ii = 0; ii < 8; ++ii) {
        float v = row[ii * 256 + t];
        s += v; q += v * v;
    }
    __shared__ float ssum[256], ssq[256];
    ssum[t] = s; ssq[t] = q;
    __syncthreads();
    for (int o = 128; o > 0; o >>= 1) {
        if (t < o) { ssum[t] += ssum[t + o]; ssq[t] += ssq[t + o]; }
        __syncthreads();
    }
    if (t == 0) {
        float mean = ssum[0] * (1.f / 2048.f);
        float var = ssq[0] * (1.f / 2048.f) - mean * mean;
        float sc = g[rh] * rsqrtf(var + cEPS);
        scale[rh] = sc;
        shift[rh] = bta[rh] - mean * sc;
    }
}

// ---------------------------------------------------------------------------
// 11) logit[e][r] = sum_h u[r*32+h] * tanh(pre2*scale+shift); grid (8 e-tiles, 16 r)
__global__ __launch_bounds__(256) void k_final(
    const float* __restrict__ pre2,
    const float* __restrict__ scale, const float* __restrict__ shift,
    const float* __restrict__ ntl_u, float* __restrict__ out) {
    int r = blockIdx.y;
    int e = blockIdx.x * 256 + threadIdx.x;
    float a = 0.f;
#pragma unroll
    for (int h = 0; h < 32; ++h) {
        int rh = r * 32 + h;
        float p = pre2[(size_t)rh * cE + e];
        a += ntl_u[rh] * ftanh(fmaf(p, scale[rh], shift[rh]));
    }
    out[(size_t)e * 16 + r] = a;
}

// ---------------------------------------------------------------------------
// 12) per-graph loss/acc/em partials
__global__ void k_loss(const float* __restrict__ out, const int* __restrict__ mask,
                       float* __restrict__ part) {
    int b = blockIdx.x, t = threadIdx.x;
    float nll = 0.f;
    int corr = 0, em = 1;
#pragma unroll
    for (int q = 0; q < 4; ++q) {
        int f = t * 4 + q;
        float x = out[(size_t)b * 1024 + f];
        int m = mask[(size_t)b * 1024 + f];
        bool gt = x > 0.f;
        bool mb = (m != 0);
        bool eq = (gt == mb);
        corr += eq ? 1 : 0;
        em &= eq ? 1 : 0;
        if (mb) nll += nls(x);
        else nll += -logf(1.f / (1.f + expf(x)) + 1e-5f);
    }
    __shared__ float rs[256];
    __shared__ int rc[256], re[256];
    rs[t] = nll; rc[t] = corr; re[t] = em;
    __syncthreads();
    for (int o = 128; o > 0; o >>= 1) {
        if (t < o) { rs[t] += rs[t + o]; rc[t] += rc[t + o]; re[t] &= re[t + o]; }
        __syncthreads();
    }
    if (t == 0) {
        part[b * 4 + 0] = rs[0];
        part[b * 4 + 1] = (float)rc[0];
        part[b * 4 + 2] = (float)re[0];
    }
}

__global__ void k_loss_fin(const float* __restrict__ part, float* __restrict__ out) {
    if (threadIdx.x == 0) {
        float nll = 0.f, corr = 0.f, em = 0.f;
        for (int b = 0; b < 32; ++b) {
            nll += part[b * 4 + 0];
            corr += part[b * 4 + 1];
            em += part[b * 4 + 2];
        }
        out[32768] = nll / 32.f;
        out[32769] = corr / 32768.f;
        out[32770] = em / 32.f;
    }
}

}  // namespace

extern "C" void kernel_launch(void* const* d_in, const int* in_sizes, int n_in,
                              void* d_out, int out_size, void* d_ws, size_t ws_size,
                              hipStream_t stream) {
    (void)in_sizes; (void)n_in; (void)out_size; (void)ws_size;
    const int* seq = (const int*)d_in[0];
    const int* p2g = (const int*)d_in[1];
    const int* idx = (const int*)d_in[2];
    const int* mask = (const int*)d_in[5];
    const float* emb = (const float*)d_in[6];
    const float* wih_f = (const float*)d_in[7];
    const float* whh_f = (const float*)d_in[8];
    const float* bih_f = (const float*)d_in[9];
    const float* bhh_f = (const float*)d_in[10];
    const float* wih_b = (const float*)d_in[11];
    const float* whh_b = (const float*)d_in[12];
    const float* bih_b = (const float*)d_in[13];
    const float* bhh_b = (const float*)d_in[14];
    const float* lsw = (const float*)d_in[15];
    const float* lsb = (const float*)d_in[16];
    const float* ldw = (const float*)d_in[17];
    const float* ldb = (const float*)d_in[18];
    const float* bn_sg = (const float*)d_in[19];
    const float* bn_sb = (const float*)d_in[20];
    const float* bn_dg = (const float*)d_in[21];
    const float* bn_db = (const float*)d_in[22];
    const float* ntlw = (const float*)d_in[23];
    const float* ntlv = (const float*)d_in[24];
    const float* ntlb = (const float*)d_in[25];
    const float* ntlu = (const float*)d_in[26];
    const float* bn2g = (const float*)d_in[27];
    const float* bn2b = (const float*)d_in[28];
    float* out = (float*)d_out;
    char* ws = (char*)d_ws;

    float* x_seq = (float*)(ws + 0);
    float* pre = (float*)(ws + 2097152);
    unsigned short* tmp = (unsigned short*)(ws + 0);
    size_t off = 33554432;
    float* h_out = (float*)(ws + off); off += 2097152;
    float* hsum = (float*)(ws + off); off += 262144;
    float* s_raw = (float*)(ws + off); off += 131072;
    float* d_raw = (float*)(ws + off); off += 131072;
    float* hd_bn = (float*)(ws + off); off += 131072;
    float* tl_bn = (float*)(ws + off); off += 131072;
    float* lsrc = (float*)(ws + off); off += 524288;
    float* ldst = (float*)(ws + off); off += 524288;
    float* pre2 = (float*)(ws + off); off += 4194304;
    float* scale = (float*)(ws + off); off += 2048;
    float* shift = (float*)(ws + off); off += 2048;
    float* part = (float*)(ws + off); off += 512;

    k_embed<<<32, 256, 0, stream>>>(seq, p2g, emb, x_seq);
    k_gemm_in<<<dim3(16, 32), 256, 0, stream>>>(x_seq, wih_f, wih_b, bih_f, bhh_f, bih_b, bhh_b, pre);
    k_lstm_m<<<4, 512, 0, stream>>>(pre, whh_f, whh_b, h_out);
    k_gather<<<256, 256, 0, stream>>>(idx, p2g, h_out, hsum);
    k_proj<<<dim3(256, 2), 128, 0, stream>>>(hsum, lsw, lsb, ldw, ldb, s_raw, d_raw);
    k_bn_nodes<<<256, 256, 0, stream>>>(s_raw, d_raw, bn_sg, bn_sb, bn_dg, bn_db, hd_bn, tl_bn);
    k_lin<<<512, 256, 0, stream>>>(ntlv, hd_bn, tl_bn, lsrc, ldst);
    k_ntl_A<<<512, 256, 0, stream>>>(hd_bn, ntlw, tmp);
    k_ntl_B<<<dim3(8, 512), 256, 0, stream>>>(tmp, tl_bn, lsrc, ldst, ntlb, pre2);
    k_bn2<<<512, 256, 0, stream>>>(pre2, bn2g, bn2b, scale, shift);
    k_final<<<dim3(8, 16), 256, 0, stream>>>(pre2, scale, shift, ntlu, out);
    k_loss<<<32, 256, 0, stream>>>(out, mask, part);
    k_loss_fin<<<1, 32, 0, stream>>>(part, out);
}

// Round 5
// 230.778 us; speedup vs baseline: 1.1694x; 1.0076x over previous
//
#include <hip/hip_runtime.h>
#include <math.h>

namespace {

constexpr int cB = 32, cL = 128, cG = 64, cD = 256;
constexpr int cHD = 128, cH = 256;
constexpr int cN = 8, cK = 4;
constexpr int cNI = 128, cRH = 512;
constexpr int cE = 2048;
constexpr float cEPS = 1e-5f;

typedef __bf16 bf16x8 __attribute__((ext_vector_type(8)));
typedef float f32x4 __attribute__((ext_vector_type(4)));

__device__ __forceinline__ f32x4 mfma16(bf16x8 a, bf16x8 b, f32x4 c) {
    return __builtin_amdgcn_mfma_f32_16x16x32_bf16(a, b, c, 0, 0, 0);
}

__device__ __forceinline__ float bf2f(unsigned short u) {
    unsigned int x = ((unsigned int)u) << 16;
    return __uint_as_float(x);
}
__device__ __forceinline__ unsigned short f2bf(float f) {
    unsigned int x = __float_as_uint(f);
    unsigned int r = (x + 0x7fffu + ((x >> 16) & 1u)) >> 16;  // RNE
    return (unsigned short)r;
}
__device__ __forceinline__ float fsig(float x) { return 1.f / (1.f + __expf(-x)); }
__device__ __forceinline__ float ftanh(float x) { return 1.f - 2.f / (__expf(2.f * x) + 1.f); }
__device__ __forceinline__ float nls(float x) {
    return (x >= 0.f) ? log1pf(expf(-x)) : (log1pf(expf(x)) - x);
}

// lgkm-only barrier: LDS ping-pong needs lgkmcnt ordering, NOT a vmcnt(0) drain.
__device__ __forceinline__ void bar_lgkm() {
    asm volatile("s_waitcnt lgkmcnt(0)\n\ts_barrier" ::: "memory");
}

// ---------------------------------------------------------------------------
// 1) token embedding + scatter_sum into groups, output layout (g, b, d)
__global__ void k_embed(const int* __restrict__ seq, const int* __restrict__ p2g,
                        const float* __restrict__ emb, float* __restrict__ x_seq) {
    __shared__ float xl[cG * cD];
    int b = blockIdx.x, t = threadIdx.x;
    for (int g = 0; g < cG; ++g) xl[g * cD + t] = 0.f;
    for (int l = 0; l < cL; ++l) {
        int tok = seq[b * cL + l];
        int g = p2g[b * cL + l];
        xl[g * cD + t] += emb[tok * cD + t];
    }
    for (int g = 0; g < cG; ++g)
        x_seq[(g * cB + b) * cD + t] = xl[g * cD + t];
}

// ---------------------------------------------------------------------------
// 2) LSTM input GEMM.  NEW pre layout: idx = ((g*256 + n4)*32 + b)*4 + r,
//    where gate index n = n4*4 + r (n<512 fwd, >=512 bwd).
__global__ __launch_bounds__(256) void k_gemm_in(
    const float* __restrict__ x_seq,
    const float* __restrict__ wih_f, const float* __restrict__ wih_b,
    const float* __restrict__ bih_f, const float* __restrict__ bhh_f,
    const float* __restrict__ bih_b, const float* __restrict__ bhh_b,
    float* __restrict__ pre) {
    __shared__ float As[64][17];
    __shared__ float Bs[16][68];
    int t = threadIdx.x;
    int n0 = blockIdx.x * 64, m0 = blockIdx.y * 64;
    int tx = t & 15, ty = t >> 4;
    float acc[4][4] = {};
    for (int k0 = 0; k0 < cD; k0 += 16) {
        {
            int r = t >> 2, c = (t & 3) * 4;
            float4 a4 = *(const float4*)(x_seq + (size_t)(m0 + r) * cD + k0 + c);
            As[r][c + 0] = a4.x; As[r][c + 1] = a4.y; As[r][c + 2] = a4.z; As[r][c + 3] = a4.w;
        }
        {
            int n = t >> 2, c = (t & 3) * 4;
            int gn = n0 + n;
            const float* wrow = (gn < 512) ? (wih_f + (size_t)gn * cD)
                                           : (wih_b + (size_t)(gn - 512) * cD);
            float4 b4 = *(const float4*)(wrow + k0 + c);
            Bs[c + 0][n] = b4.x; Bs[c + 1][n] = b4.y; Bs[c + 2][n] = b4.z; Bs[c + 3][n] = b4.w;
        }
        __syncthreads();
#pragma unroll
        for (int k = 0; k < 16; ++k) {
            float a[4], bb[4];
#pragma unroll
            for (int i = 0; i < 4; ++i) a[i] = As[ty * 4 + i][k];
#pragma unroll
            for (int j = 0; j < 4; ++j) bb[j] = Bs[k][tx * 4 + j];
#pragma unroll
            for (int i = 0; i < 4; ++i)
#pragma unroll
                for (int j = 0; j < 4; ++j) acc[i][j] += a[i] * bb[j];
        }
        __syncthreads();
    }
#pragma unroll
    for (int i = 0; i < 4; ++i) {
        int m = m0 + ty * 4 + i;
        int g = m >> 5, b = m & 31;
        float4 v;
        float* vv = &v.x;
#pragma unroll
        for (int j = 0; j < 4; ++j) {
            int n = n0 + tx * 4 + j;
            float bias = (n < 512) ? (bih_f[n] + bhh_f[n]) : (bih_b[n - 512] + bhh_b[n - 512]);
            vv[j] = acc[i][j] + bias;
        }
        *(float4*)(pre + (((size_t)g * 256 + (n0 >> 2) + tx) * 32 + b) * 4) = v;
    }
}

// ---------------------------------------------------------------------------
// 3) MFMA LSTM v3. 4 blocks = (dir, bhalf); 512 thr = 8 waves (2/SIMD).
//    A = Whh fragments stationary in VGPRs; B = h(t-1) from swizzled LDS ping-pong.
//    pre prefetch: 4x 256B-contiguous wave loads. h_out store: 16x64B chunks.
__device__ __forceinline__ void lstm_step(
    f32x4 (&acc)[4], float (&cst)[4], const bf16x8 (&wf)[4][4],
    const unsigned short* __restrict__ hr, unsigned short* __restrict__ hw,
    const int (&rdo)[4], int wro,
    const float* __restrict__ preb, int gpre, bool dopre,
    float* __restrict__ hob, int g) {
    bf16x8 hf[4];
#pragma unroll
    for (int kf = 0; kf < 4; ++kf)
        hf[kf] = *(const bf16x8*)((const char*)hr + rdo[kf]);
#pragma unroll
    for (int kf = 0; kf < 4; ++kf)
#pragma unroll
        for (int q = 0; q < 4; ++q)
            acc[q] = mfma16(wf[q][kf], hf[kf], acc[q]);
    float hv[4];
#pragma unroll
    for (int r = 0; r < 4; ++r) {
        float ig = fsig(acc[0][r]);
        float fg = fsig(acc[1][r]);
        float gg = ftanh(acc[2][r]);
        float og = fsig(acc[3][r]);
        float cv = fg * cst[r] + ig * gg;
        cst[r] = cv;
        hv[r] = og * ftanh(cv);
    }
    if (dopre) {
#pragma unroll
        for (int q = 0; q < 4; ++q)
            acc[q] = *(const f32x4*)(preb + (size_t)gpre * 32768 + q * 4096);
    }
    unsigned int p0 = (unsigned int)f2bf(hv[0]) | ((unsigned int)f2bf(hv[1]) << 16);
    unsigned int p1 = (unsigned int)f2bf(hv[2]) | ((unsigned int)f2bf(hv[3]) << 16);
    *(uint2*)((char*)hw + wro) = make_uint2(p0, p1);
    *(float4*)(hob + (size_t)g * 8192) = make_float4(hv[0], hv[1], hv[2], hv[3]);
    bar_lgkm();
}

__global__ __launch_bounds__(512, 2) void k_lstm_m(
    const float* __restrict__ pre,
    const float* __restrict__ whh_f, const float* __restrict__ whh_b,
    float* __restrict__ h_out) {
    __shared__ __align__(16) unsigned short hl[2][2048];  // [buf][b(16) x h(128)] bf16
    int t = threadIdx.x;
    int w = t >> 6, l = t & 63, lc = l & 15, lk = l >> 4;
    int dir = blockIdx.x >> 1, bg = (blockIdx.x & 1) * 16;
    const float* whh = dir ? whh_b : whh_f;
    // stationary A-fragments: wave w, tile q -> Whh rows n = q*128 + w*16 + lc
    bf16x8 wf[4][4];
#pragma unroll
    for (int q = 0; q < 4; ++q) {
        int n = q * 128 + w * 16 + lc;
#pragma unroll
        for (int kf = 0; kf < 4; ++kf) {
            const float* src = whh + (size_t)n * 128 + kf * 32 + lk * 8;
            float4 s0 = *(const float4*)src, s1 = *(const float4*)(src + 4);
            bf16x8 v;
            v[0] = (__bf16)s0.x; v[1] = (__bf16)s0.y; v[2] = (__bf16)s0.z; v[3] = (__bf16)s0.w;
            v[4] = (__bf16)s1.x; v[5] = (__bf16)s1.y; v[6] = (__bf16)s1.z; v[7] = (__bf16)s1.w;
            wf[q][kf] = v;
        }
    }
    // zero h(-1) buffer (hl[1])
    *(uint2*)&hl[1][t * 4] = make_uint2(0u, 0u);
    // per-lane bases (new layouts)
    const float* preb = pre + ((size_t)(dir * 128 + w * 4 + lk) * 32 + (bg + lc)) * 4;
    float* hob = h_out + ((size_t)(dir * 32 + bg + lc) * 128 + w * 16 + lk * 4);
    int rdo[4];
#pragma unroll
    for (int kf = 0; kf < 4; ++kf)
        rdo[kf] = (lc * 256 + kf * 64 + lk * 16) ^ ((lc & 7) << 4);
    int wro = (lc * 256 + w * 32 + lk * 8) ^ ((lc & 7) << 4);
    f32x4 accA[4], accB[4];
    float cst[4] = {0.f, 0.f, 0.f, 0.f};
    int g0 = dir ? 63 : 0;
    int sgn = dir ? -1 : 1;
#pragma unroll
    for (int q = 0; q < 4; ++q) accA[q] = *(const f32x4*)(preb + (size_t)g0 * 32768 + q * 4096);
#pragma unroll
    for (int q = 0; q < 4; ++q) accB[q] = *(const f32x4*)(preb + (size_t)(g0 + sgn) * 32768 + q * 4096);
    bar_lgkm();  // zero-init visible
    for (int s = 0; s < 64; s += 2) {
        int ga = g0 + sgn * s;
        lstm_step(accA, cst, wf, hl[1], hl[0], rdo, wro, preb,
                  ga + 2 * sgn, s < 62, hob, ga);
        lstm_step(accB, cst, wf, hl[0], hl[1], rdo, wro, preb,
                  ga + 3 * sgn, s < 61, hob, ga + sgn);
    }
}

// ---------------------------------------------------------------------------
// 4) gather + scatter_sum over K. h_out layout [g][dir][b][h]:
//    idx = g*8192 + (dir*32+b)*128 + h
__global__ void k_gather(const int* __restrict__ idx, const int* __restrict__ p2g,
                         const float* __restrict__ h_out, float* __restrict__ hsum) {
    int bn = blockIdx.x;
    int b = bn >> 3;
    int t = threadIdx.x;  // channel: t<128 fwd, t>=128 bwd
    int dirq = t >> 7, hh = t & 127;
    float acc = 0.f;
    for (int k = 0; k < cK; ++k) {
        int l = idx[bn * cK + k];
        int g = p2g[b * cL + l];
        acc += h_out[(size_t)g * 8192 + (size_t)(dirq * 32 + b) * 128 + hh];
    }
    hsum[(size_t)bn * cH + t] = acc;
}

// ---------------------------------------------------------------------------
// 5) per-node projection (src / dst selected by blockIdx.y)
__global__ __launch_bounds__(128) void k_proj(
    const float* __restrict__ hsum,
    const float* __restrict__ w_src, const float* __restrict__ b_src,
    const float* __restrict__ w_dst, const float* __restrict__ b_dst,
    float* __restrict__ s_raw, float* __restrict__ d_raw) {
    int n = blockIdx.x, which = blockIdx.y, t = threadIdx.x;
    __shared__ float xr[cH];
    xr[t] = hsum[(size_t)n * cH + t];
    xr[t + 128] = hsum[(size_t)n * cH + t + 128];
    __syncthreads();
    const float* w = which ? w_dst : w_src;
    const float* bb = which ? b_dst : b_src;
    const float* wr = w + (size_t)t * cH;
    float acc = bb[t];
#pragma unroll 8
    for (int k = 0; k < cH; k += 4) {
        float4 w4 = *(const float4*)(wr + k);
        acc += w4.x * xr[k] + w4.y * xr[k + 1] + w4.z * xr[k + 2] + w4.w * xr[k + 3];
    }
    (which ? d_raw : s_raw)[(size_t)n * cNI + t] = acc;
}

// ---------------------------------------------------------------------------
// 6) BatchNorm over the 256 nodes (== BN over E, each node appears 8x)
__global__ void k_bn_nodes(const float* __restrict__ s_raw, const float* __restrict__ d_raw,
                           const float* __restrict__ g_src, const float* __restrict__ b_src,
                           const float* __restrict__ g_dst, const float* __restrict__ b_dst,
                           float* __restrict__ hd_bn, float* __restrict__ tl_bn) {
    int ch = blockIdx.x, which = ch >> 7, cc = ch & 127;
    int t = threadIdx.x;
    const float* raw = which ? d_raw : s_raw;
    float v = raw[(size_t)t * cNI + cc];
    __shared__ float ssum[256], ssq[256];
    ssum[t] = v;
    ssq[t] = v * v;
    __syncthreads();
    for (int o = 128; o > 0; o >>= 1) {
        if (t < o) { ssum[t] += ssum[t + o]; ssq[t] += ssq[t + o]; }
        __syncthreads();
    }
    float mean = ssum[0] * (1.f / 256.f);
    float var = ssq[0] * (1.f / 256.f) - mean * mean;
    float gam = which ? g_dst[cc] : g_src[cc];
    float bet = which ? b_dst[cc] : b_src[cc];
    float scale = gam * rsqrtf(var + cEPS);
    (which ? tl_bn : hd_bn)[(size_t)t * cNI + cc] = (v - mean) * scale + bet;
}

// ---------------------------------------------------------------------------
// 7) linear part of NTL per node: Lsrc[rh][n], Ldst[rh][n]
__global__ void k_lin(const float* __restrict__ ntl_v,
                      const float* __restrict__ hd_bn, const float* __restrict__ tl_bn,
                      float* __restrict__ lsrc, float* __restrict__ ldst) {
    int rh = blockIdx.x, t = threadIdx.x;
    __shared__ float vr[256];
    vr[t] = ntl_v[(size_t)rh * 256 + t];
    __syncthreads();
    const float* hr = hd_bn + (size_t)t * cNI;
    const float* tr = tl_bn + (size_t)t * cNI;
    float a1 = 0.f, a2 = 0.f;
#pragma unroll 8
    for (int i = 0; i < cNI; i += 4) {
        float4 h4 = *(const float4*)(hr + i);
        float4 t4 = *(const float4*)(tr + i);
        a1 += h4.x * vr[i] + h4.y * vr[i + 1] + h4.z * vr[i + 2] + h4.w * vr[i + 3];
        a2 += t4.x * vr[128 + i] + t4.y * vr[128 + i + 1] + t4.z * vr[128 + i + 2] + t4.w * vr[128 + i + 3];
    }
    lsrc[(size_t)rh * 256 + t] = a1;
    ldst[(size_t)rh * 256 + t] = a2;
}

// ---------------------------------------------------------------------------
// 8) MFMA NTL-A: tmp_frag[rh] = hd_bn(256x128) @ W[rh](128x128), bf16 frag-dump.
__global__ __launch_bounds__(256, 2) void k_ntl_A(
    const float* __restrict__ hd_bn, const float* __restrict__ ntl_w,
    unsigned short* __restrict__ tmp) {
    __shared__ __align__(16) unsigned short wl[128 * 128];
    int rh = blockIdx.x, t = threadIdx.x;
    int w = t >> 6, l = t & 63, lc = l & 15, lk = l >> 4;
    {
        const float* wbase = ntl_w + (size_t)rh * 16384;
        int k = t >> 1, c0 = (t & 1) * 64;
        int sw = ((k >> 3) & 3) << 4;
#pragma unroll
        for (int u = 0; u < 8; ++u) {
            const float* src = wbase + k * 128 + c0 + u * 8;
            float4 f0 = *(const float4*)src, f1 = *(const float4*)(src + 4);
            bf16x8 v;
            v[0] = (__bf16)f0.x; v[1] = (__bf16)f0.y; v[2] = (__bf16)f0.z; v[3] = (__bf16)f0.w;
            v[4] = (__bf16)f1.x; v[5] = (__bf16)f1.y; v[6] = (__bf16)f1.z; v[7] = (__bf16)f1.w;
            *(bf16x8*)((char*)wl + ((k * 256 + (c0 + u * 8) * 2) ^ sw)) = v;
        }
    }
    __syncthreads();
    f32x4 acc[4][8] = {};
#pragma unroll
    for (int kf = 0; kf < 4; ++kf) {
        bf16x8 af[4];
#pragma unroll
        for (int mt = 0; mt < 4; ++mt) {
            int m = w * 64 + mt * 16 + lc;
            const float* ap = hd_bn + (size_t)m * 128 + kf * 32 + lk * 8;
            float4 a0 = *(const float4*)ap, a1 = *(const float4*)(ap + 4);
            bf16x8 v;
            v[0] = (__bf16)a0.x; v[1] = (__bf16)a0.y; v[2] = (__bf16)a0.z; v[3] = (__bf16)a0.w;
            v[4] = (__bf16)a1.x; v[5] = (__bf16)a1.y; v[6] = (__bf16)a1.z; v[7] = (__bf16)a1.w;
            af[mt] = v;
        }
#pragma unroll
        for (int nt = 0; nt < 8; ++nt) {
            int kb = (kf * 32 + lk * 8) * 256;
            int jb = (nt * 16 + lc) * 2;
            bf16x8 bv = *(const bf16x8*)((char*)wl + ((kb + jb) ^ (lk << 4)));
#pragma unroll
            for (int mt = 0; mt < 4; ++mt) acc[mt][nt] = mfma16(af[mt], bv, acc[mt][nt]);
        }
    }
#pragma unroll
    for (int mt = 0; mt < 4; ++mt) {
#pragma unroll
        for (int nt = 0; nt < 8; ++nt) {
            unsigned int lo = (unsigned int)f2bf(acc[mt][nt][0]) | ((unsigned int)f2bf(acc[mt][nt][1]) << 16);
            unsigned int hi = (unsigned int)f2bf(acc[mt][nt][2]) | ((unsigned int)f2bf(acc[mt][nt][3]) << 16);
            size_t off = (size_t)rh * 32768 + (size_t)((((w * 4 + mt) * 8 + nt) * 64 + l) * 4);
            *(uint2*)(tmp + off) = make_uint2(lo, hi);
        }
    }
}

// ---------------------------------------------------------------------------
// 9) bilinear dot + linear + bias -> pre2[rh][e]; decodes frag-dump tmp.
__global__ __launch_bounds__(256) void k_ntl_B(
    const unsigned short* __restrict__ tmp, const float* __restrict__ tl_bn,
    const float* __restrict__ lsrc, const float* __restrict__ ldst,
    const float* __restrict__ ntl_b, float* __restrict__ pre2) {
    int bgid = blockIdx.x;
    int rh = blockIdx.y;
    int t = threadIdx.x;
    int n0 = bgid * 32;
    __shared__ float tm[32][132];
    __shared__ float tl[32][132];
    {
        const uint4* src = (const uint4*)(tmp + (size_t)rh * 32768 +
                                          (size_t)(bgid >> 1) * 8192 + (size_t)(bgid & 1) * 4096);
#pragma unroll
        for (int rep = 0; rep < 2; ++rep) {
            int q = t + rep * 256;
            uint4 uv = src[q];
            unsigned int wds[4] = {uv.x, uv.y, uv.z, uv.w};
            int e0 = q * 8;
#pragma unroll
            for (int ui = 0; ui < 4; ++ui) {
                int e = e0 + ui * 2;
                int mt_l = e >> 11;
                int nt = (e >> 8) & 7;
                int ln = (e >> 2) & 63;
                int r = e & 3;
                int m = mt_l * 16 + (ln >> 4) * 4 + r;
                int j = nt * 16 + (ln & 15);
                tm[m][j] = bf2f((unsigned short)(wds[ui] & 0xffff));
                tm[m + 1][j] = bf2f((unsigned short)(wds[ui] >> 16));
            }
        }
        int r = t >> 3;
        int c0 = (t & 7) * 16;
        const float4* fsrc = (const float4*)(tl_bn + (size_t)(n0 + r) * cNI + c0);
        float4 f0 = fsrc[0], f1 = fsrc[1], f2v = fsrc[2], f3 = fsrc[3];
        float* frow = &tl[r][c0];
        frow[0] = f0.x; frow[1] = f0.y; frow[2] = f0.z; frow[3] = f0.w;
        frow[4] = f1.x; frow[5] = f1.y; frow[6] = f1.z; frow[7] = f1.w;
        frow[8] = f2v.x; frow[9] = f2v.y; frow[10] = f2v.z; frow[11] = f2v.w;
        frow[12] = f3.x; frow[13] = f3.y; frow[14] = f3.z; frow[15] = f3.w;
    }
    __syncthreads();
    int b_l = t >> 6, p = t & 63, i = p >> 3, j = p & 7;
    const float* ta = &tm[b_l * 8 + i][0];
    const float* tb = &tl[b_l * 8 + j][0];
    float s = 0.f;
#pragma unroll 8
    for (int k = 0; k < 128; ++k) s += ta[k] * tb[k];
    int e = bgid * 256 + t;
    int bglob = bgid * 4 + b_l;
    int un = bglob * 8 + i, vn = bglob * 8 + j;
    pre2[(size_t)rh * cE + e] = s + lsrc[(size_t)rh * 256 + un] + ldst[(size_t)rh * 256 + vn] + ntl_b[rh];
}

// ---------------------------------------------------------------------------
// 10) BN stats over E per rh channel -> scale/shift
__global__ void k_bn2(const float* __restrict__ pre2,
                      const float* __restrict__ g, const float* __restrict__ bta,
                      float* __restrict__ scale, float* __restrict__ shift) {
    int rh = blockIdx.x, t = threadIdx.x;
    const float* row = pre2 + (size_t)rh * cE;
    float s = 0.f, q = 0.f;
#pragma unroll
    for (int ii = 0; ii < 8; ++ii) {
        float v = row[ii * 256 + t];
        s += v; q += v * v;
    }
    __shared__ float ssum[256], ssq[256];
    ssum[t] = s; ssq[t] = q;
    __syncthreads();
    for (int o = 128; o > 0; o >>= 1) {
        if (t < o) { ssum[t] += ssum[t + o]; ssq[t] += ssq[t + o]; }
        __syncthreads();
    }
    if (t == 0) {
        float mean = ssum[0] * (1.f / 2048.f);
        float var = ssq[0] * (1.f / 2048.f) - mean * mean;
        float sc = g[rh] * rsqrtf(var + cEPS);
        scale[rh] = sc;
        shift[rh] = bta[rh] - mean * sc;
    }
}

// ---------------------------------------------------------------------------
// 11) logit[e][r] = sum_h u[r*32+h] * tanh(pre2*scale+shift); grid (8 e-tiles, 16 r)
__global__ __launch_bounds__(256) void k_final(
    const float* __restrict__ pre2,
    const float* __restrict__ scale, const float* __restrict__ shift,
    const float* __restrict__ ntl_u, float* __restrict__ out) {
    int r = blockIdx.y;
    int e = blockIdx.x * 256 + threadIdx.x;
    float a = 0.f;
#pragma unroll
    for (int h = 0; h < 32; ++h) {
        int rh = r * 32 + h;
        float p = pre2[(size_t)rh * cE + e];
        a += ntl_u[rh] * ftanh(fmaf(p, scale[rh], shift[rh]));
    }
    out[(size_t)e * 16 + r] = a;
}

// ---------------------------------------------------------------------------
// 12) per-graph loss/acc/em partials
__global__ void k_loss(const float* __restrict__ out, const int* __restrict__ mask,
                       float* __restrict__ part) {
    int b = blockIdx.x, t = threadIdx.x;
    float nll = 0.f;
    int corr = 0, em = 1;
#pragma unroll
    for (int q = 0; q < 4; ++q) {
        int f = t * 4 + q;
        float x = out[(size_t)b * 1024 + f];
        int m = mask[(size_t)b * 1024 + f];
        bool gt = x > 0.f;
        bool mb = (m != 0);
        bool eq = (gt == mb);
        corr += eq ? 1 : 0;
        em &= eq ? 1 : 0;
        if (mb) nll += nls(x);
        else nll += -logf(1.f / (1.f + expf(x)) + 1e-5f);
    }
    __shared__ float rs[256];
    __shared__ int rc[256], re[256];
    rs[t] = nll; rc[t] = corr; re[t] = em;
    __syncthreads();
    for (int o = 128; o > 0; o >>= 1) {
        if (t < o) { rs[t] += rs[t + o]; rc[t] += rc[t + o]; re[t] &= re[t + o]; }
        __syncthreads();
    }
    if (t == 0) {
        part[b * 4 + 0] = rs[0];
        part[b * 4 + 1] = (float)rc[0];
        part[b * 4 + 2] = (float)re[0];
    }
}

__global__ void k_loss_fin(const float* __restrict__ part, float* __restrict__ out) {
    if (threadIdx.x == 0) {
        float nll = 0.f, corr = 0.f, em = 0.f;
        for (int b = 0; b < 32; ++b) {
            nll += part[b * 4 + 0];
            corr += part[b * 4 + 1];
            em += part[b * 4 + 2];
        }
        out[32768] = nll / 32.f;
        out[32769] = corr / 32768.f;
        out[32770] = em / 32.f;
    }
}

}  // namespace

extern "C" void kernel_launch(void* const* d_in, const int* in_sizes, int n_in,
                              void* d_out, int out_size, void* d_ws, size_t ws_size,
                              hipStream_t stream) {
    (void)in_sizes; (void)n_in; (void)out_size; (void)ws_size;
    const int* seq = (const int*)d_in[0];
    const int* p2g = (const int*)d_in[1];
    const int* idx = (const int*)d_in[2];
    const int* mask = (const int*)d_in[5];
    const float* emb = (const float*)d_in[6];
    const float* wih_f = (const float*)d_in[7];
    const float* whh_f = (const float*)d_in[8];
    const float* bih_f = (const float*)d_in[9];
    const float* bhh_f = (const float*)d_in[10];
    const float* wih_b = (const float*)d_in[11];
    const float* whh_b = (const float*)d_in[12];
    const float* bih_b = (const float*)d_in[13];
    const float* bhh_b = (const float*)d_in[14];
    const float* lsw = (const float*)d_in[15];
    const float* lsb = (const float*)d_in[16];
    const float* ldw = (const float*)d_in[17];
    const float* ldb = (const float*)d_in[18];
    const float* bn_sg = (const float*)d_in[19];
    const float* bn_sb = (const float*)d_in[20];
    const float* bn_dg = (const float*)d_in[21];
    const float* bn_db = (const float*)d_in[22];
    const float* ntlw = (const float*)d_in[23];
    const float* ntlv = (const float*)d_in[24];
    const float* ntlb = (const float*)d_in[25];
    const float* ntlu = (const float*)d_in[26];
    const float* bn2g = (const float*)d_in[27];
    const float* bn2b = (const float*)d_in[28];
    float* out = (float*)d_out;
    char* ws = (char*)d_ws;

    float* x_seq = (float*)(ws + 0);
    float* pre = (float*)(ws + 2097152);
    unsigned short* tmp = (unsigned short*)(ws + 0);
    size_t off = 33554432;
    float* h_out = (float*)(ws + off); off += 2097152;
    float* hsum = (float*)(ws + off); off += 262144;
    float* s_raw = (float*)(ws + off); off += 131072;
    float* d_raw = (float*)(ws + off); off += 131072;
    float* hd_bn = (float*)(ws + off); off += 131072;
    float* tl_bn = (float*)(ws + off); off += 131072;
    float* lsrc = (float*)(ws + off); off += 524288;
    float* ldst = (float*)(ws + off); off += 524288;
    float* pre2 = (float*)(ws + off); off += 4194304;
    float* scale = (float*)(ws + off); off += 2048;
    float* shift = (float*)(ws + off); off += 2048;
    float* part = (float*)(ws + off); off += 512;

    k_embed<<<32, 256, 0, stream>>>(seq, p2g, emb, x_seq);
    k_gemm_in<<<dim3(16, 32), 256, 0, stream>>>(x_seq, wih_f, wih_b, bih_f, bhh_f, bih_b, bhh_b, pre);
    k_lstm_m<<<4, 512, 0, stream>>>(pre, whh_f, whh_b, h_out);
    k_gather<<<256, 256, 0, stream>>>(idx, p2g, h_out, hsum);
    k_proj<<<dim3(256, 2), 128, 0, stream>>>(hsum, lsw, lsb, ldw, ldb, s_raw, d_raw);
    k_bn_nodes<<<256, 256, 0, stream>>>(s_raw, d_raw, bn_sg, bn_sb, bn_dg, bn_db, hd_bn, tl_bn);
    k_lin<<<512, 256, 0, stream>>>(ntlv, hd_bn, tl_bn, lsrc, ldst);
    k_ntl_A<<<512, 256, 0, stream>>>(hd_bn, ntlw, tmp);
    k_ntl_B<<<dim3(8, 512), 256, 0, stream>>>(tmp, tl_bn, lsrc, ldst, ntlb, pre2);
    k_bn2<<<512, 256, 0, stream>>>(pre2, bn2g, bn2b, scale, shift);
    k_final<<<dim3(8, 16), 256, 0, stream>>>(pre2, scale, shift, ntlu, out);
    k_loss<<<32, 256, 0, stream>>>(out, mask, part);
    k_loss_fin<<<1, 32, 0, stream>>>(part, out);
}

// Round 6
// 183.192 us; speedup vs baseline: 1.4731x; 1.2598x over previous
//
#include <hip/hip_runtime.h>
#include <math.h>

namespace {

constexpr int cB = 32, cL = 128, cG = 64, cD = 256;
constexpr int cHD = 128, cH = 256;
constexpr int cN = 8, cK = 4;
constexpr int cNI = 128, cRH = 512;
constexpr int cE = 2048;
constexpr float cEPS = 1e-5f;

typedef __bf16 bf16x8 __attribute__((ext_vector_type(8)));
typedef float f32x4 __attribute__((ext_vector_type(4)));

__device__ __forceinline__ f32x4 mfma16(bf16x8 a, bf16x8 b, f32x4 c) {
    return __builtin_amdgcn_mfma_f32_16x16x32_bf16(a, b, c, 0, 0, 0);
}

__device__ __forceinline__ float bf2f(unsigned short u) {
    unsigned int x = ((unsigned int)u) << 16;
    return __uint_as_float(x);
}
__device__ __forceinline__ unsigned short f2bf(float f) {
    unsigned int x = __float_as_uint(f);
    unsigned int r = (x + 0x7fffu + ((x >> 16) & 1u)) >> 16;  // RNE
    return (unsigned short)r;
}
__device__ __forceinline__ float frcp(float x) { return __builtin_amdgcn_rcpf(x); }
// fast sigmoid/tanh: v_exp + v_rcp, NO IEEE division (error budget is huge)
__device__ __forceinline__ float fsig(float x) { return frcp(1.f + __expf(-x)); }
__device__ __forceinline__ float ftanh(float x) { return 1.f - 2.f * frcp(__expf(2.f * x) + 1.f); }
__device__ __forceinline__ float nls(float x) {
    return (x >= 0.f) ? log1pf(expf(-x)) : (log1pf(expf(x)) - x);
}

// lgkm-only barrier: LDS ping-pong needs lgkmcnt ordering, NOT a vmcnt(0) drain.
__device__ __forceinline__ void bar_lgkm() {
    asm volatile("s_waitcnt lgkmcnt(0)\n\ts_barrier" ::: "memory");
}

// ---------------------------------------------------------------------------
// 1) token embedding + scatter_sum into groups, output layout (g, b, d)
__global__ void k_embed(const int* __restrict__ seq, const int* __restrict__ p2g,
                        const float* __restrict__ emb, float* __restrict__ x_seq) {
    __shared__ float xl[cG * cD];
    int b = blockIdx.x, t = threadIdx.x;
    for (int g = 0; g < cG; ++g) xl[g * cD + t] = 0.f;
    for (int l = 0; l < cL; ++l) {
        int tok = seq[b * cL + l];
        int g = p2g[b * cL + l];
        xl[g * cD + t] += emb[tok * cD + t];
    }
    for (int g = 0; g < cG; ++g)
        x_seq[(g * cB + b) * cD + t] = xl[g * cD + t];
}

// ---------------------------------------------------------------------------
// 2) LSTM input GEMM.  pre layout: idx = ((g*256 + n4)*32 + b)*4 + r,
//    gate index n = n4*4 + r (n<512 fwd, >=512 bwd).
__global__ __launch_bounds__(256) void k_gemm_in(
    const float* __restrict__ x_seq,
    const float* __restrict__ wih_f, const float* __restrict__ wih_b,
    const float* __restrict__ bih_f, const float* __restrict__ bhh_f,
    const float* __restrict__ bih_b, const float* __restrict__ bhh_b,
    float* __restrict__ pre) {
    __shared__ float As[64][17];
    __shared__ float Bs[16][68];
    int t = threadIdx.x;
    int n0 = blockIdx.x * 64, m0 = blockIdx.y * 64;
    int tx = t & 15, ty = t >> 4;
    float acc[4][4] = {};
    for (int k0 = 0; k0 < cD; k0 += 16) {
        {
            int r = t >> 2, c = (t & 3) * 4;
            float4 a4 = *(const float4*)(x_seq + (size_t)(m0 + r) * cD + k0 + c);
            As[r][c + 0] = a4.x; As[r][c + 1] = a4.y; As[r][c + 2] = a4.z; As[r][c + 3] = a4.w;
        }
        {
            int n = t >> 2, c = (t & 3) * 4;
            int gn = n0 + n;
            const float* wrow = (gn < 512) ? (wih_f + (size_t)gn * cD)
                                           : (wih_b + (size_t)(gn - 512) * cD);
            float4 b4 = *(const float4*)(wrow + k0 + c);
            Bs[c + 0][n] = b4.x; Bs[c + 1][n] = b4.y; Bs[c + 2][n] = b4.z; Bs[c + 3][n] = b4.w;
        }
        __syncthreads();
#pragma unroll
        for (int k = 0; k < 16; ++k) {
            float a[4], bb[4];
#pragma unroll
            for (int i = 0; i < 4; ++i) a[i] = As[ty * 4 + i][k];
#pragma unroll
            for (int j = 0; j < 4; ++j) bb[j] = Bs[k][tx * 4 + j];
#pragma unroll
            for (int i = 0; i < 4; ++i)
#pragma unroll
                for (int j = 0; j < 4; ++j) acc[i][j] += a[i] * bb[j];
        }
        __syncthreads();
    }
#pragma unroll
    for (int i = 0; i < 4; ++i) {
        int m = m0 + ty * 4 + i;
        int g = m >> 5, b = m & 31;
        float4 v;
        float* vv = &v.x;
#pragma unroll
        for (int j = 0; j < 4; ++j) {
            int n = n0 + tx * 4 + j;
            float bias = (n < 512) ? (bih_f[n] + bhh_f[n]) : (bih_b[n - 512] + bhh_b[n - 512]);
            vv[j] = acc[i][j] + bias;
        }
        *(float4*)(pre + (((size_t)g * 256 + (n0 >> 2) + tx) * 32 + b) * 4) = v;
    }
}

// ---------------------------------------------------------------------------
// 3) MFMA LSTM v4. 4 blocks = (dir, bhalf); 512 thr = 8 waves (2/SIMD).
__device__ __forceinline__ void lstm_step(
    f32x4 (&acc)[4], float (&cst)[4], const bf16x8 (&wf)[4][4],
    const unsigned short* __restrict__ hr, unsigned short* __restrict__ hw,
    const int (&rdo)[4], int wro,
    const float* __restrict__ preb, int gpre, bool dopre,
    unsigned short* __restrict__ hob, int g) {
    bf16x8 hf[4];
#pragma unroll
    for (int kf = 0; kf < 4; ++kf)
        hf[kf] = *(const bf16x8*)((const char*)hr + rdo[kf]);
#pragma unroll
    for (int kf = 0; kf < 4; ++kf)
#pragma unroll
        for (int q = 0; q < 4; ++q)
            acc[q] = mfma16(wf[q][kf], hf[kf], acc[q]);
    float hv[4];
#pragma unroll
    for (int r = 0; r < 4; ++r) {
        float ig = fsig(acc[0][r]);
        float fg = fsig(acc[1][r]);
        float gg = ftanh(acc[2][r]);
        float og = fsig(acc[3][r]);
        float cv = fg * cst[r] + ig * gg;
        cst[r] = cv;
        hv[r] = og * ftanh(cv);
    }
    if (dopre) {
#pragma unroll
        for (int q = 0; q < 4; ++q)
            acc[q] = *(const f32x4*)(preb + (size_t)gpre * 32768 + q * 4096);
    }
    unsigned int p0 = (unsigned int)f2bf(hv[0]) | ((unsigned int)f2bf(hv[1]) << 16);
    unsigned int p1 = (unsigned int)f2bf(hv[2]) | ((unsigned int)f2bf(hv[3]) << 16);
    *(uint2*)((char*)hw + wro) = make_uint2(p0, p1);
    *(uint2*)(hob + (size_t)g * 8192) = make_uint2(p0, p1);
    bar_lgkm();
}

__global__ __launch_bounds__(512, 2) void k_lstm_m(
    const float* __restrict__ pre,
    const float* __restrict__ whh_f, const float* __restrict__ whh_b,
    unsigned short* __restrict__ h_out) {
    __shared__ __align__(16) unsigned short hl[2][2048];  // [buf][b(16) x h(128)] bf16
    int t = threadIdx.x;
    int w = t >> 6, l = t & 63, lc = l & 15, lk = l >> 4;
    int dir = blockIdx.x >> 1, bg = (blockIdx.x & 1) * 16;
    const float* whh = dir ? whh_b : whh_f;
    bf16x8 wf[4][4];
#pragma unroll
    for (int q = 0; q < 4; ++q) {
        int n = q * 128 + w * 16 + lc;
#pragma unroll
        for (int kf = 0; kf < 4; ++kf) {
            const float* src = whh + (size_t)n * 128 + kf * 32 + lk * 8;
            float4 s0 = *(const float4*)src, s1 = *(const float4*)(src + 4);
            bf16x8 v;
            v[0] = (__bf16)s0.x; v[1] = (__bf16)s0.y; v[2] = (__bf16)s0.z; v[3] = (__bf16)s0.w;
            v[4] = (__bf16)s1.x; v[5] = (__bf16)s1.y; v[6] = (__bf16)s1.z; v[7] = (__bf16)s1.w;
            wf[q][kf] = v;
        }
    }
    *(uint2*)&hl[1][t * 4] = make_uint2(0u, 0u);
    const float* preb = pre + ((size_t)(dir * 128 + w * 4 + lk) * 32 + (bg + lc)) * 4;
    unsigned short* hob = h_out + ((size_t)(dir * 32 + bg + lc) * 128 + w * 16 + lk * 4);
    // full 4-bit XOR swizzle: physical = logical ^ (lc<<4)
    int rdo[4];
#pragma unroll
    for (int kf = 0; kf < 4; ++kf)
        rdo[kf] = (lc * 256 + kf * 64 + lk * 16) ^ (lc << 4);
    int wro = (lc * 256 + w * 32 + lk * 8) ^ (lc << 4);
    f32x4 accA[4], accB[4];
    float cst[4] = {0.f, 0.f, 0.f, 0.f};
    int g0 = dir ? 63 : 0;
    int sgn = dir ? -1 : 1;
#pragma unroll
    for (int q = 0; q < 4; ++q) accA[q] = *(const f32x4*)(preb + (size_t)g0 * 32768 + q * 4096);
#pragma unroll
    for (int q = 0; q < 4; ++q) accB[q] = *(const f32x4*)(preb + (size_t)(g0 + sgn) * 32768 + q * 4096);
    bar_lgkm();  // zero-init visible
    for (int s = 0; s < 64; s += 2) {
        int ga = g0 + sgn * s;
        lstm_step(accA, cst, wf, hl[1], hl[0], rdo, wro, preb,
                  ga + 2 * sgn, s < 62, hob, ga);
        lstm_step(accB, cst, wf, hl[0], hl[1], rdo, wro, preb,
                  ga + 3 * sgn, s < 61, hob, ga + sgn);
    }
}

// ---------------------------------------------------------------------------
// 4) fused gather(+sum over K) + src/dst projection.  256 blocks = node.
__global__ __launch_bounds__(256) void k_gather_proj(
    const int* __restrict__ idx, const int* __restrict__ p2g,
    const unsigned short* __restrict__ h_out,
    const float* __restrict__ w_src, const float* __restrict__ b_src,
    const float* __restrict__ w_dst, const float* __restrict__ b_dst,
    float* __restrict__ s_raw, float* __restrict__ d_raw) {
    int bn = blockIdx.x;
    int b = bn >> 3;
    int t = threadIdx.x;
    int dirq = t >> 7, hh = t & 127;
    __shared__ float xr[cH];
    float acc = 0.f;
#pragma unroll
    for (int k = 0; k < cK; ++k) {
        int l = idx[bn * cK + k];
        int g = p2g[b * cL + l];
        acc += bf2f(h_out[(size_t)g * 8192 + (size_t)(dirq * 32 + b) * 128 + hh]);
    }
    xr[t] = acc;
    __syncthreads();
    int which = t >> 7, c = t & 127;
    const float* w = which ? w_dst : w_src;
    const float* bb = which ? b_dst : b_src;
    const float* wr = w + (size_t)c * cH;
    float s = bb[c];
#pragma unroll 8
    for (int k = 0; k < cH; k += 4) {
        float4 w4 = *(const float4*)(wr + k);
        s += w4.x * xr[k] + w4.y * xr[k + 1] + w4.z * xr[k + 2] + w4.w * xr[k + 3];
    }
    (which ? d_raw : s_raw)[(size_t)bn * cNI + c] = s;
}

// ---------------------------------------------------------------------------
// 5) BatchNorm over the 256 nodes
__global__ void k_bn_nodes(const float* __restrict__ s_raw, const float* __restrict__ d_raw,
                           const float* __restrict__ g_src, const float* __restrict__ b_src,
                           const float* __restrict__ g_dst, const float* __restrict__ b_dst,
                           float* __restrict__ hd_bn, float* __restrict__ tl_bn) {
    int ch = blockIdx.x, which = ch >> 7, cc = ch & 127;
    int t = threadIdx.x;
    const float* raw = which ? d_raw : s_raw;
    float v = raw[(size_t)t * cNI + cc];
    __shared__ float ssum[256], ssq[256];
    ssum[t] = v;
    ssq[t] = v * v;
    __syncthreads();
    for (int o = 128; o > 0; o >>= 1) {
        if (t < o) { ssum[t] += ssum[t + o]; ssq[t] += ssq[t + o]; }
        __syncthreads();
    }
    float mean = ssum[0] * (1.f / 256.f);
    float var = ssq[0] * (1.f / 256.f) - mean * mean;
    float gam = which ? g_dst[cc] : g_src[cc];
    float bet = which ? b_dst[cc] : b_src[cc];
    float scale = gam * rsqrtf(var + cEPS);
    (which ? tl_bn : hd_bn)[(size_t)t * cNI + cc] = (v - mean) * scale + bet;
}

// ---------------------------------------------------------------------------
// 6) MFMA NTL-A + fused lin: tmp_frag[rh] = hd_bn @ W[rh] (bf16 frag-dump);
//    lsrc[rh][n] = v[0:128].hd_bn[n]; ldst[rh][n] = v[128:256].tl_bn[n].
__global__ __launch_bounds__(256, 2) void k_ntl_A(
    const float* __restrict__ hd_bn, const float* __restrict__ tl_bn,
    const float* __restrict__ ntl_w, const float* __restrict__ ntl_v,
    unsigned short* __restrict__ tmp,
    float* __restrict__ lsrc, float* __restrict__ ldst) {
    __shared__ __align__(16) unsigned short wl[128 * 128];
    __shared__ float vsh[256];
    int rh = blockIdx.x, t = threadIdx.x;
    int w = t >> 6, l = t & 63, lc = l & 15, lk = l >> 4;
    vsh[t] = ntl_v[(size_t)rh * 256 + t];
    {
        const float* wbase = ntl_w + (size_t)rh * 16384;
        int k = t >> 1, c0 = (t & 1) * 64;
        int sw = ((k >> 3) & 3) << 4;
#pragma unroll
        for (int u = 0; u < 8; ++u) {
            const float* src = wbase + k * 128 + c0 + u * 8;
            float4 f0 = *(const float4*)src, f1 = *(const float4*)(src + 4);
            bf16x8 v;
            v[0] = (__bf16)f0.x; v[1] = (__bf16)f0.y; v[2] = (__bf16)f0.z; v[3] = (__bf16)f0.w;
            v[4] = (__bf16)f1.x; v[5] = (__bf16)f1.y; v[6] = (__bf16)f1.z; v[7] = (__bf16)f1.w;
            *(bf16x8*)((char*)wl + ((k * 256 + (c0 + u * 8) * 2) ^ sw)) = v;
        }
    }
    __syncthreads();
    // fused lin (node t)
    {
        const float* hr = hd_bn + (size_t)t * cNI;
        const float* tr = tl_bn + (size_t)t * cNI;
        float a1 = 0.f, a2 = 0.f;
#pragma unroll 8
        for (int i = 0; i < cNI; i += 4) {
            float4 h4 = *(const float4*)(hr + i);
            float4 t4 = *(const float4*)(tr + i);
            a1 += h4.x * vsh[i] + h4.y * vsh[i + 1] + h4.z * vsh[i + 2] + h4.w * vsh[i + 3];
            a2 += t4.x * vsh[128 + i] + t4.y * vsh[128 + i + 1] + t4.z * vsh[128 + i + 2] + t4.w * vsh[128 + i + 3];
        }
        lsrc[(size_t)rh * 256 + t] = a1;
        ldst[(size_t)rh * 256 + t] = a2;
    }
    f32x4 acc[4][8] = {};
#pragma unroll
    for (int kf = 0; kf < 4; ++kf) {
        bf16x8 af[4];
#pragma unroll
        for (int mt = 0; mt < 4; ++mt) {
            int m = w * 64 + mt * 16 + lc;
            const float* ap = hd_bn + (size_t)m * 128 + kf * 32 + lk * 8;
            float4 a0 = *(const float4*)ap, a1 = *(const float4*)(ap + 4);
            bf16x8 v;
            v[0] = (__bf16)a0.x; v[1] = (__bf16)a0.y; v[2] = (__bf16)a0.z; v[3] = (__bf16)a0.w;
            v[4] = (__bf16)a1.x; v[5] = (__bf16)a1.y; v[6] = (__bf16)a1.z; v[7] = (__bf16)a1.w;
            af[mt] = v;
        }
#pragma unroll
        for (int nt = 0; nt < 8; ++nt) {
            int kb = (kf * 32 + lk * 8) * 256;
            int jb = (nt * 16 + lc) * 2;
            bf16x8 bv = *(const bf16x8*)((char*)wl + ((kb + jb) ^ (lk << 4)));
#pragma unroll
            for (int mt = 0; mt < 4; ++mt) acc[mt][nt] = mfma16(af[mt], bv, acc[mt][nt]);
        }
    }
#pragma unroll
    for (int mt = 0; mt < 4; ++mt) {
#pragma unroll
        for (int nt = 0; nt < 8; ++nt) {
            unsigned int lo = (unsigned int)f2bf(acc[mt][nt][0]) | ((unsigned int)f2bf(acc[mt][nt][1]) << 16);
            unsigned int hi = (unsigned int)f2bf(acc[mt][nt][2]) | ((unsigned int)f2bf(acc[mt][nt][3]) << 16);
            size_t off = (size_t)rh * 32768 + (size_t)((((w * 4 + mt) * 8 + nt) * 64 + l) * 4);
            *(uint2*)(tmp + off) = make_uint2(lo, hi);
        }
    }
}

// ---------------------------------------------------------------------------
// 7) bilinear dot + linear + bias -> pre2[rh][e]; decodes frag-dump tmp.
__global__ __launch_bounds__(256) void k_ntl_B(
    const unsigned short* __restrict__ tmp, const float* __restrict__ tl_bn,
    const float* __restrict__ lsrc, const float* __restrict__ ldst,
    const float* __restrict__ ntl_b, float* __restrict__ pre2) {
    int bgid = blockIdx.x;
    int rh = blockIdx.y;
    int t = threadIdx.x;
    int n0 = bgid * 32;
    __shared__ float tm[32][132];
    __shared__ float tl[32][132];
    {
        const uint4* src = (const uint4*)(tmp + (size_t)rh * 32768 +
                                          (size_t)(bgid >> 1) * 8192 + (size_t)(bgid & 1) * 4096);
#pragma unroll
        for (int rep = 0; rep < 2; ++rep) {
            int q = t + rep * 256;
            uint4 uv = src[q];
            unsigned int wds[4] = {uv.x, uv.y, uv.z, uv.w};
            int e0 = q * 8;
#pragma unroll
            for (int ui = 0; ui < 4; ++ui) {
                int e = e0 + ui * 2;
                int mt_l = e >> 11;
                int nt = (e >> 8) & 7;
                int ln = (e >> 2) & 63;
                int r = e & 3;
                int m = mt_l * 16 + (ln >> 4) * 4 + r;
                int j = nt * 16 + (ln & 15);
                tm[m][j] = bf2f((unsigned short)(wds[ui] & 0xffff));
                tm[m + 1][j] = bf2f((unsigned short)(wds[ui] >> 16));
            }
        }
        int r = t >> 3;
        int c0 = (t & 7) * 16;
        const float4* fsrc = (const float4*)(tl_bn + (size_t)(n0 + r) * cNI + c0);
        float4 f0 = fsrc[0], f1 = fsrc[1], f2v = fsrc[2], f3 = fsrc[3];
        float* frow = &tl[r][c0];
        frow[0] = f0.x; frow[1] = f0.y; frow[2] = f0.z; frow[3] = f0.w;
        frow[4] = f1.x; frow[5] = f1.y; frow[6] = f1.z; frow[7] = f1.w;
        frow[8] = f2v.x; frow[9] = f2v.y; frow[10] = f2v.z; frow[11] = f2v.w;
        frow[12] = f3.x; frow[13] = f3.y; frow[14] = f3.z; frow[15] = f3.w;
    }
    __syncthreads();
    int b_l = t >> 6, p = t & 63, i = p >> 3, j = p & 7;
    const float* ta = &tm[b_l * 8 + i][0];
    const float* tb = &tl[b_l * 8 + j][0];
    float s = 0.f;
#pragma unroll 8
    for (int k = 0; k < 128; ++k) s += ta[k] * tb[k];
    int e = bgid * 256 + t;
    int bglob = bgid * 4 + b_l;
    int un = bglob * 8 + i, vn = bglob * 8 + j;
    pre2[(size_t)rh * cE + e] = s + lsrc[(size_t)rh * 256 + un] + ldst[(size_t)rh * 256 + vn] + ntl_b[rh];
}

// ---------------------------------------------------------------------------
// 8) BN stats over E per rh channel -> scale/shift
__global__ void k_bn2(const float* __restrict__ pre2,
                      const float* __restrict__ g, const float* __restrict__ bta,
                      float* __restrict__ scale, float* __restrict__ shift) {
    int rh = blockIdx.x, t = threadIdx.x;
    const float* row = pre2 + (size_t)rh * cE;
    float s = 0.f, q = 0.f;
#pragma unroll
    for (int ii = 0; ii < 8; ++ii) {
        float v = row[ii * 256 + t];
        s += v; q += v * v;
    }
    __shared__ float ssum[256], ssq[256];
    ssum[t] = s; ssq[t] = q;
    __syncthreads();
    for (int o = 128; o > 0; o >>= 1) {
        if (t < o) { ssum[t] += ssum[t + o]; ssq[t] += ssq[t + o]; }
        __syncthreads();
    }
    if (t == 0) {
        float mean = ssum[0] * (1.f / 2048.f);
        float var = ssq[0] * (1.f / 2048.f) - mean * mean;
        float sc = g[rh] * rsqrtf(var + cEPS);
        scale[rh] = sc;
        shift[rh] = bta[rh] - mean * sc;
    }
}

// ---------------------------------------------------------------------------
// 9) logit[e][r] = sum_h u[r*32+h] * tanh(pre2*scale+shift)
__global__ __launch_bounds__(256) void k_final(
    const float* __restrict__ pre2,
    const float* __restrict__ scale, const float* __restrict__ shift,
    const float* __restrict__ ntl_u, float* __restrict__ out) {
    int r = blockIdx.y;
    int e = blockIdx.x * 256 + threadIdx.x;
    float a = 0.f;
#pragma unroll
    for (int h = 0; h < 32; ++h) {
        int rh = r * 32 + h;
        float p = pre2[(size_t)rh * cE + e];
        a += ntl_u[rh] * ftanh(fmaf(p, scale[rh], shift[rh]));
    }
    out[(size_t)e * 16 + r] = a;
}

// ---------------------------------------------------------------------------
// 10) per-graph loss/acc/em partials
__global__ void k_loss(const float* __restrict__ out, const int* __restrict__ mask,
                       float* __restrict__ part) {
    int b = blockIdx.x, t = threadIdx.x;
    float nll = 0.f;
    int corr = 0, em = 1;
#pragma unroll
    for (int q = 0; q < 4; ++q) {
        int f = t * 4 + q;
        float x = out[(size_t)b * 1024 + f];
        int m = mask[(size_t)b * 1024 + f];
        bool gt = x > 0.f;
        bool mb = (m != 0);
        bool eq = (gt == mb);
        corr += eq ? 1 : 0;
        em &= eq ? 1 : 0;
        if (mb) nll += nls(x);
        else nll += -logf(1.f / (1.f + expf(x)) + 1e-5f);
    }
    __shared__ float rs[256];
    __shared__ int rc[256], re[256];
    rs[t] = nll; rc[t] = corr; re[t] = em;
    __syncthreads();
    for (int o = 128; o > 0; o >>= 1) {
        if (t < o) { rs[t] += rs[t + o]; rc[t] += rc[t + o]; re[t] &= re[t + o]; }
        __syncthreads();
    }
    if (t == 0) {
        part[b * 4 + 0] = rs[0];
        part[b * 4 + 1] = (float)rc[0];
        part[b * 4 + 2] = (float)re[0];
    }
}

__global__ void k_loss_fin(const float* __restrict__ part, float* __restrict__ out) {
    if (threadIdx.x == 0) {
        float nll = 0.f, corr = 0.f, em = 0.f;
        for (int b = 0; b < 32; ++b) {
            nll += part[b * 4 + 0];
            corr += part[b * 4 + 1];
            em += part[b * 4 + 2];
        }
        out[32768] = nll / 32.f;
        out[32769] = corr / 32768.f;
        out[32770] = em / 32.f;
    }
}

}  // namespace

extern "C" void kernel_launch(void* const* d_in, const int* in_sizes, int n_in,
                              void* d_out, int out_size, void* d_ws, size_t ws_size,
                              hipStream_t stream) {
    (void)in_sizes; (void)n_in; (void)out_size; (void)ws_size;
    const int* seq = (const int*)d_in[0];
    const int* p2g = (const int*)d_in[1];
    const int* idx = (const int*)d_in[2];
    const int* mask = (const int*)d_in[5];
    const float* emb = (const float*)d_in[6];
    const float* wih_f = (const float*)d_in[7];
    const float* whh_f = (const float*)d_in[8];
    const float* bih_f = (const float*)d_in[9];
    const float* bhh_f = (const float*)d_in[10];
    const float* wih_b = (const float*)d_in[11];
    const float* whh_b = (const float*)d_in[12];
    const float* bih_b = (const float*)d_in[13];
    const float* bhh_b = (const float*)d_in[14];
    const float* lsw = (const float*)d_in[15];
    const float* lsb = (const float*)d_in[16];
    const float* ldw = (const float*)d_in[17];
    const float* ldb = (const float*)d_in[18];
    const float* bn_sg = (const float*)d_in[19];
    const float* bn_sb = (const float*)d_in[20];
    const float* bn_dg = (const float*)d_in[21];
    const float* bn_db = (const float*)d_in[22];
    const float* ntlw = (const float*)d_in[23];
    const float* ntlv = (const float*)d_in[24];
    const float* ntlb = (const float*)d_in[25];
    const float* ntlu = (const float*)d_in[26];
    const float* bn2g = (const float*)d_in[27];
    const float* bn2b = (const float*)d_in[28];
    float* out = (float*)d_out;
    char* ws = (char*)d_ws;

    float* x_seq = (float*)(ws + 0);
    float* pre = (float*)(ws + 2097152);
    unsigned short* tmp = (unsigned short*)(ws + 0);
    size_t off = 33554432;
    unsigned short* h_out = (unsigned short*)(ws + off); off += 1048576;
    float* s_raw = (float*)(ws + off); off += 131072;
    float* d_raw = (float*)(ws + off); off += 131072;
    float* hd_bn = (float*)(ws + off); off += 131072;
    float* tl_bn = (float*)(ws + off); off += 131072;
    float* lsrc = (float*)(ws + off); off += 524288;
    float* ldst = (float*)(ws + off); off += 524288;
    float* pre2 = (float*)(ws + off); off += 4194304;
    float* scale = (float*)(ws + off); off += 2048;
    float* shift = (float*)(ws + off); off += 2048;
    float* part = (float*)(ws + off); off += 512;

    k_embed<<<32, 256, 0, stream>>>(seq, p2g, emb, x_seq);
    k_gemm_in<<<dim3(16, 32), 256, 0, stream>>>(x_seq, wih_f, wih_b, bih_f, bhh_f, bih_b, bhh_b, pre);
    k_lstm_m<<<4, 512, 0, stream>>>(pre, whh_f, whh_b, h_out);
    k_gather_proj<<<256, 256, 0, stream>>>(idx, p2g, h_out, lsw, lsb, ldw, ldb, s_raw, d_raw);
    k_bn_nodes<<<256, 256, 0, stream>>>(s_raw, d_raw, bn_sg, bn_sb, bn_dg, bn_db, hd_bn, tl_bn);
    k_ntl_A<<<512, 256, 0, stream>>>(hd_bn, tl_bn, ntlw, ntlv, tmp, lsrc, ldst);
    k_ntl_B<<<dim3(8, 512), 256, 0, stream>>>(tmp, tl_bn, lsrc, ldst, ntlb, pre2);
    k_bn2<<<512, 256, 0, stream>>>(pre2, bn2g, bn2b, scale, shift);
    k_final<<<dim3(8, 16), 256, 0, stream>>>(pre2, scale, shift, ntlu, out);
    k_loss<<<32, 256, 0, stream>>>(out, mask, part);
    k_loss_fin<<<1, 32, 0, stream>>>(part, out);
}